// Round 4
// baseline (1187.421 us; speedup 1.0000x reference)
//
#include <hip/hip_runtime.h>
#include <stdint.h>

#define N_NODES 100000
#define N_EDGES 1600000
#define F 128
#define NPB 128                      // nodes per bucket
#define NB ((N_NODES + NPB - 1) / NPB)  // 782 buckets

// ---------------- preprocessing ----------------

__global__ void k_init(float* deg, int* cnt, int n) {
    int i = blockIdx.x * blockDim.x + threadIdx.x;
    if (i < n) { deg[i] = 1.0f; cnt[i] = 0; }
}

// degree accumulation + node histogram in one pass over ei
__global__ void k_deg_hist(const int* __restrict__ ei, const float* __restrict__ w,
                           float* deg, int* cnt, int e) {
    int i = blockIdx.x * blockDim.x + threadIdx.x;
    if (i < e) {
        int d = ei[N_EDGES + i];
        atomicAdd(&deg[d], w[i]);
        atomicAdd(&cnt[d], 1);
    }
}

__global__ void k_dinv(float* deg, int n) {
    int i = blockIdx.x * blockDim.x + threadIdx.x;
    if (i < n) deg[i] = rsqrtf(deg[i]);
}

// ---------------- hierarchical exclusive scan ----------------
__launch_bounds__(256)
__global__ void k_bsum(const int* __restrict__ cnt, int* __restrict__ bsum, int n) {
    int b = blockIdx.x, tid = threadIdx.x;
    int base = b * 1024 + tid * 4;
    int s = 0;
#pragma unroll
    for (int j = 0; j < 4; j++)
        if (base + j < n) s += cnt[base + j];
    for (int off = 32; off; off >>= 1) s += __shfl_down(s, off, 64);
    __shared__ int ws[4];
    if ((tid & 63) == 0) ws[tid >> 6] = s;
    __syncthreads();
    if (tid == 0) bsum[b] = ws[0] + ws[1] + ws[2] + ws[3];
}

__launch_bounds__(128)
__global__ void k_bscan(int* bsum, int nb, int* row_last) {
    __shared__ int ls[128];
    int tid = threadIdx.x;
    int v = (tid < nb) ? bsum[tid] : 0;
    ls[tid] = v;
    __syncthreads();
    for (int off = 1; off < 128; off <<= 1) {
        int t = (tid >= off) ? ls[tid - off] : 0;
        __syncthreads();
        ls[tid] += t;
        __syncthreads();
    }
    int ex = tid ? ls[tid - 1] : 0;
    if (tid < nb) bsum[tid] = ex;
    if (tid == 0) *row_last = N_EDGES;
}

// block-local scan; writes row, pos copy, and bucket cursors (row at each 128-node boundary)
__launch_bounds__(256)
__global__ void k_scan2(int* __restrict__ cnt_pos, const int* __restrict__ boff,
                        int* __restrict__ row, int* __restrict__ bcur, int n) {
    __shared__ int ls[256];
    int b = blockIdx.x, tid = threadIdx.x;
    int base = b * 1024 + tid * 4;
    int v[4];
    int s = 0;
#pragma unroll
    for (int j = 0; j < 4; j++) {
        v[j] = (base + j < n) ? cnt_pos[base + j] : 0;
        s += v[j];
    }
    ls[tid] = s;
    __syncthreads();
    for (int off = 1; off < 256; off <<= 1) {
        int t = (tid >= off) ? ls[tid - off] : 0;
        __syncthreads();
        ls[tid] += t;
        __syncthreads();
    }
    int run = boff[b] + (tid ? ls[tid - 1] : 0);
#pragma unroll
    for (int j = 0; j < 4; j++) {
        int node = base + j;
        if (node < n) {
            row[node] = run;
            if ((node & (NPB - 1)) == 0) bcur[node >> 7] = run;
            run += v[j];
        }
    }
}

// ---------------- bucketed CSR build ----------------
// phase A: compute enorm inline, append packed edge to dst bucket (dense write frontier)
__global__ void k_bucketA(const int* __restrict__ ei, const float* __restrict__ w,
                          const float* __restrict__ dinv, int* bcur, int2* __restrict__ stage,
                          int e) {
    int i = blockIdx.x * blockDim.x + threadIdx.x;
    if (i < e) {
        int s = ei[i];
        int d = ei[N_EDGES + i];
        float en = dinv[s] * w[i] * dinv[d];
        int b = d >> 7;
        int local = d & (NPB - 1);
        int p = atomicAdd(&bcur[b], 1);
        stage[p] = make_int2((local << 17) | s, __float_as_int(en));
    }
}

// phase B: permute bucket contents into per-node CSR segments (LDS cursors, 16KB write window)
__launch_bounds__(256)
__global__ void k_placeB(const int2* __restrict__ stage, const int* __restrict__ row,
                         int2* __restrict__ edges, int n) {
    __shared__ int cur[NPB];
    int b = blockIdx.x, tid = threadIdx.x;
    int n0 = b << 7;
    int nn = min(NPB, n - n0);
    if (tid < nn) cur[tid] = row[n0 + tid];
    __syncthreads();
    int lo = row[n0];
    int hi = row[min(n0 + NPB, n)];
    for (int j = lo + tid; j < hi; j += 256) {
        int2 e = stage[j];
        int l = e.x >> 17;
        int src = e.x & 0x1FFFF;
        int p = atomicAdd(&cur[l], 1);
        edges[p] = make_int2(src, e.y);
    }
}

// ---------------- fp32 GEMM: H[nrows x 128] = X[nrows x 128] @ W[128 x 128] ----------------

#define GKT 16
#define GS 132

__launch_bounds__(256, 4)
__global__ void k_gemm(const float* __restrict__ X, const float* __restrict__ W,
                       float* __restrict__ H, int nrows) {
    __shared__ float As[GKT * GS];
    __shared__ float Bs[GKT * GS];
    int tid = threadIdx.x;
    int tx = tid & 15, ty = tid >> 4;
    int r0 = blockIdx.x * 128;
    float acc[8][8];
#pragma unroll
    for (int i = 0; i < 8; i++)
#pragma unroll
        for (int j = 0; j < 8; j++) acc[i][j] = 0.f;

    for (int k0 = 0; k0 < F; k0 += GKT) {
#pragma unroll
        for (int it = 0; it < 2; it++) {
            int f = tid + it * 256;
            int r = f >> 2;
            int kc = (f & 3) * 4;
            float4 v = make_float4(0.f, 0.f, 0.f, 0.f);
            if (r0 + r < nrows)
                v = *(const float4*)&X[(size_t)(r0 + r) * F + k0 + kc];
            As[(kc + 0) * GS + r] = v.x;
            As[(kc + 1) * GS + r] = v.y;
            As[(kc + 2) * GS + r] = v.z;
            As[(kc + 3) * GS + r] = v.w;
        }
#pragma unroll
        for (int it = 0; it < 2; it++) {
            int f = tid + it * 256;
            int kk = f >> 5;
            int cc = (f & 31) * 4;
            *(float4*)&Bs[kk * GS + cc] = *(const float4*)&W[(size_t)(k0 + kk) * F + cc];
        }
        __syncthreads();
#pragma unroll
        for (int kk = 0; kk < GKT; kk++) {
            float a[8], b[8];
            *(float4*)&a[0] = *(const float4*)&As[kk * GS + ty * 8];
            *(float4*)&a[4] = *(const float4*)&As[kk * GS + ty * 8 + 4];
            *(float4*)&b[0] = *(const float4*)&Bs[kk * GS + tx * 8];
            *(float4*)&b[4] = *(const float4*)&Bs[kk * GS + tx * 8 + 4];
#pragma unroll
            for (int i = 0; i < 8; i++)
#pragma unroll
                for (int j = 0; j < 8; j++)
                    acc[i][j] = fmaf(a[i], b[j], acc[i][j]);
        }
        __syncthreads();
    }
#pragma unroll
    for (int i = 0; i < 8; i++) {
        int r = r0 + ty * 8 + i;
        if (r < nrows) {
            *(float4*)&H[(size_t)r * F + tx * 8] = *(float4*)&acc[i][0];
            *(float4*)&H[(size_t)r * F + tx * 8 + 4] = *(float4*)&acc[i][4];
        }
    }
}

// ---------------- aggregation (packed int2 edges) ----------------

__launch_bounds__(256)
__global__ void k_agg(const float* __restrict__ H, const int* __restrict__ row,
                      const int2* __restrict__ edges,
                      const float* __restrict__ dinv, const float* __restrict__ bias,
                      float* __restrict__ out, int n, int relu) {
    int node = blockIdx.x * 4 + (threadIdx.x >> 6);
    if (node >= n) return;
    int lane = threadIdx.x & 63;
    int half = lane >> 5;
    int sub = lane & 31;
    float4 acc = make_float4(0.f, 0.f, 0.f, 0.f);
    int beg = row[node], end = row[node + 1];
    int deg = end - beg;
    int t = half;
    for (; t + 2 < deg; t += 4) {
        int2 e0 = edges[beg + t];
        int2 e1 = edges[beg + t + 2];
        float w0 = __int_as_float(e0.y);
        float w1 = __int_as_float(e1.y);
        float4 v0 = *(const float4*)&H[(size_t)e0.x * F + sub * 4];
        float4 v1 = *(const float4*)&H[(size_t)e1.x * F + sub * 4];
        acc.x = fmaf(w0, v0.x, acc.x);
        acc.y = fmaf(w0, v0.y, acc.y);
        acc.z = fmaf(w0, v0.z, acc.z);
        acc.w = fmaf(w0, v0.w, acc.w);
        acc.x = fmaf(w1, v1.x, acc.x);
        acc.y = fmaf(w1, v1.y, acc.y);
        acc.z = fmaf(w1, v1.z, acc.z);
        acc.w = fmaf(w1, v1.w, acc.w);
    }
    for (; t < deg; t += 2) {
        int2 e0 = edges[beg + t];
        float w0 = __int_as_float(e0.y);
        float4 v0 = *(const float4*)&H[(size_t)e0.x * F + sub * 4];
        acc.x = fmaf(w0, v0.x, acc.x);
        acc.y = fmaf(w0, v0.y, acc.y);
        acc.z = fmaf(w0, v0.z, acc.z);
        acc.w = fmaf(w0, v0.w, acc.w);
    }
    acc.x += __shfl_xor(acc.x, 32, 64);
    acc.y += __shfl_xor(acc.y, 32, 64);
    acc.z += __shfl_xor(acc.z, 32, 64);
    acc.w += __shfl_xor(acc.w, 32, 64);
    if (lane < 32) {
        float di = dinv[node];
        float sn = di * di;
        float4 h = *(const float4*)&H[(size_t)node * F + lane * 4];
        float4 b = *(const float4*)&bias[lane * 4];
        acc.x = fmaf(sn, h.x, acc.x) + b.x;
        acc.y = fmaf(sn, h.y, acc.y) + b.y;
        acc.z = fmaf(sn, h.z, acc.z) + b.z;
        acc.w = fmaf(sn, h.w, acc.w) + b.w;
        if (relu) {
            acc.x = fmaxf(acc.x, 0.f);
            acc.y = fmaxf(acc.y, 0.f);
            acc.z = fmaxf(acc.z, 0.f);
            acc.w = fmaxf(acc.w, 0.f);
        }
        *(float4*)&out[(size_t)node * F + lane * 4] = acc;
    }
}

// ---------------- final layer ----------------

__launch_bounds__(256)
__global__ void k_dot(const float* __restrict__ H, const float* __restrict__ Wf,
                      float* __restrict__ s, int n) {
    int node = blockIdx.x * 4 + (threadIdx.x >> 6);
    int lane = threadIdx.x & 63;
    if (node >= n) return;
    float2 h = *(const float2*)&H[(size_t)node * F + lane * 2];
    float2 w = *(const float2*)&Wf[lane * 2];
    float p = h.x * w.x + h.y * w.y;
    for (int off = 32; off; off >>= 1) p += __shfl_down(p, off, 64);
    if (lane == 0) s[node] = p;
}

__global__ void k_aggs(const float* __restrict__ s, const int* __restrict__ row,
                       const int2* __restrict__ edges,
                       const float* __restrict__ dinv, const float* __restrict__ bf,
                       float* __restrict__ out, int n) {
    int i = blockIdx.x * blockDim.x + threadIdx.x;
    if (i >= n) return;
    float di = dinv[i];
    float acc = di * di * s[i];
    int beg = row[i], end = row[i + 1];
    for (int j = beg; j < end; j++) {
        int2 e = edges[j];
        acc = fmaf(__int_as_float(e.y), s[e.x], acc);
    }
    out[i] = acc + bf[0];
}

// ---------------- host launch ----------------

extern "C" void kernel_launch(void* const* d_in, const int* in_sizes, int n_in,
                              void* d_out, int out_size, void* d_ws, size_t ws_size,
                              hipStream_t stream) {
    const float* x    = (const float*)d_in[0];
    const int*   ei   = (const int*)d_in[1];
    const float* ew   = (const float*)d_in[2];
    const float* Win  = (const float*)d_in[3];
    const float* bin  = (const float*)d_in[4];
    const float* Wmid = (const float*)d_in[5];
    const float* bmid = (const float*)d_in[6];
    const float* Wfin = (const float*)d_in[7];
    const float* bfin = (const float*)d_in[8];
    float* out = (float*)d_out;

    char* ws = (char*)d_ws;
    size_t off = 0;
    auto alloc = [&](size_t bytes) -> char* {
        char* p = ws + off;
        off = (off + bytes + 255) & ~(size_t)255;
        return p;
    };
    float* dinv  = (float*)alloc((size_t)N_NODES * 4);
    int*   row   = (int*)alloc((size_t)(N_NODES + 1) * 4);
    int*   pos   = (int*)alloc((size_t)N_NODES * 4);     // node histogram / scan scratch
    int2*  edges = (int2*)alloc((size_t)N_EDGES * 8);    // final packed CSR
    int*   bcur  = (int*)alloc((size_t)NB * 4);
    int*   bsum  = (int*)alloc(128 * 4);
    float* ha    = (float*)alloc((size_t)N_NODES * F * 4);
    float* hb    = (float*)alloc((size_t)N_NODES * F * 4);
    int2*  stage = (int2*)ha;   // aliased: consumed by k_placeB before gemm1 writes ha
    float* sbuf  = ha;          // aliased: used after last gemm

    dim3 b256(256);
    int gN = (N_NODES + 255) / 256;
    int gE = (N_EDGES + 255) / 256;
    int gW = (N_NODES + 3) / 4;
    int gG = (N_NODES + 127) / 128;
    int gS = (N_NODES + 1023) / 1024;

    hipLaunchKernelGGL(k_init, dim3(gN), b256, 0, stream, dinv, pos, N_NODES);
    hipLaunchKernelGGL(k_deg_hist, dim3(gE), b256, 0, stream, ei, ew, dinv, pos, N_EDGES);
    hipLaunchKernelGGL(k_dinv, dim3(gN), b256, 0, stream, dinv, N_NODES);
    hipLaunchKernelGGL(k_bsum, dim3(gS), b256, 0, stream, pos, bsum, N_NODES);
    hipLaunchKernelGGL(k_bscan, dim3(1), dim3(128), 0, stream, bsum, gS, &row[N_NODES]);
    hipLaunchKernelGGL(k_scan2, dim3(gS), b256, 0, stream, pos, bsum, row, bcur, N_NODES);
    hipLaunchKernelGGL(k_bucketA, dim3(gE), b256, 0, stream, ei, ew, dinv, bcur, stage, N_EDGES);
    hipLaunchKernelGGL(k_placeB, dim3(NB), b256, 0, stream, stage, row, edges, N_NODES);

    hipLaunchKernelGGL(k_gemm, dim3(gG), b256, 0, stream, x, Win, ha, N_NODES);
    hipLaunchKernelGGL(k_agg, dim3(gW), b256, 0, stream, ha, row, edges, dinv, bin, hb, N_NODES, 1);
    hipLaunchKernelGGL(k_gemm, dim3(gG), b256, 0, stream, hb, Wmid, ha, N_NODES);
    hipLaunchKernelGGL(k_agg, dim3(gW), b256, 0, stream, ha, row, edges, dinv, bmid, hb, N_NODES, 1);
    hipLaunchKernelGGL(k_gemm, dim3(gG), b256, 0, stream, hb, Wmid, ha, N_NODES);
    hipLaunchKernelGGL(k_agg, dim3(gW), b256, 0, stream, ha, row, edges, dinv, bmid, hb, N_NODES, 1);
    hipLaunchKernelGGL(k_dot, dim3(gW), b256, 0, stream, hb, Wfin, sbuf, N_NODES);
    hipLaunchKernelGGL(k_aggs, dim3(gN), b256, 0, stream, sbuf, row, edges, dinv, bfin, out, N_NODES);
}

// Round 5
// 893.134 us; speedup vs baseline: 1.3295x; 1.3295x over previous
//
#include <hip/hip_runtime.h>
#include <stdint.h>

#define N_NODES 100000
#define N_EDGES 1600000
#define F 128
#define NPB 4                         // nodes per bucket (atomic contention vs frontier tradeoff)
#define NB (N_NODES / NPB)            // 25000 buckets (N divisible by 4)

// ---------------- preprocessing ----------------

__global__ void k_init(float* deg, int* cnt, int n) {
    int i = blockIdx.x * blockDim.x + threadIdx.x;
    if (i < n) { deg[i] = 1.0f; cnt[i] = 0; }
}

// degree accumulation + node histogram in one pass over ei
__global__ void k_deg_hist(const int* __restrict__ ei, const float* __restrict__ w,
                           float* deg, int* cnt, int e) {
    int i = blockIdx.x * blockDim.x + threadIdx.x;
    if (i < e) {
        int d = ei[N_EDGES + i];
        atomicAdd(&deg[d], w[i]);
        atomicAdd(&cnt[d], 1);
    }
}

__global__ void k_dinv(float* deg, int n) {
    int i = blockIdx.x * blockDim.x + threadIdx.x;
    if (i < n) deg[i] = rsqrtf(deg[i]);
}

// ---------------- hierarchical exclusive scan ----------------
__launch_bounds__(256)
__global__ void k_bsum(const int* __restrict__ cnt, int* __restrict__ bsum, int n) {
    int b = blockIdx.x, tid = threadIdx.x;
    int base = b * 1024 + tid * 4;
    int s = 0;
#pragma unroll
    for (int j = 0; j < 4; j++)
        if (base + j < n) s += cnt[base + j];
    for (int off = 32; off; off >>= 1) s += __shfl_down(s, off, 64);
    __shared__ int ws[4];
    if ((tid & 63) == 0) ws[tid >> 6] = s;
    __syncthreads();
    if (tid == 0) bsum[b] = ws[0] + ws[1] + ws[2] + ws[3];
}

__launch_bounds__(128)
__global__ void k_bscan(int* bsum, int nb, int* row_last) {
    __shared__ int ls[128];
    int tid = threadIdx.x;
    int v = (tid < nb) ? bsum[tid] : 0;
    ls[tid] = v;
    __syncthreads();
    for (int off = 1; off < 128; off <<= 1) {
        int t = (tid >= off) ? ls[tid - off] : 0;
        __syncthreads();
        ls[tid] += t;
        __syncthreads();
    }
    int ex = tid ? ls[tid - 1] : 0;
    if (tid < nb) bsum[tid] = ex;
    if (tid == 0) *row_last = N_EDGES;
}

// block-local scan; writes row, pos copy, and per-bucket cursors (row at each NPB boundary)
__launch_bounds__(256)
__global__ void k_scan2(int* __restrict__ cnt_pos, const int* __restrict__ boff,
                        int* __restrict__ row, int* __restrict__ bcur, int n) {
    __shared__ int ls[256];
    int b = blockIdx.x, tid = threadIdx.x;
    int base = b * 1024 + tid * 4;
    int v[4];
    int s = 0;
#pragma unroll
    for (int j = 0; j < 4; j++) {
        v[j] = (base + j < n) ? cnt_pos[base + j] : 0;
        s += v[j];
    }
    ls[tid] = s;
    __syncthreads();
    for (int off = 1; off < 256; off <<= 1) {
        int t = (tid >= off) ? ls[tid - off] : 0;
        __syncthreads();
        ls[tid] += t;
        __syncthreads();
    }
    int run = boff[b] + (tid ? ls[tid - 1] : 0);
#pragma unroll
    for (int j = 0; j < 4; j++) {
        int node = base + j;
        if (node < n) {
            row[node] = run;
            if ((node & (NPB - 1)) == 0) bcur[node / NPB] = run;
            run += v[j];
        }
    }
}

// ---------------- bucketed CSR build ----------------
// phase A: enorm inline, append packed edge to dst's 4-node bucket.
// 25k cursors -> ~64 edges/cursor -> atomic serial floor ~12us (443cyc/same-addr atomic, measured R4)
__global__ void k_bucketA(const int* __restrict__ ei, const float* __restrict__ w,
                          const float* __restrict__ dinv, int* bcur, int2* __restrict__ stage,
                          int e) {
    int i = blockIdx.x * blockDim.x + threadIdx.x;
    if (i < e) {
        int s = ei[i];
        int d = ei[N_EDGES + i];
        float en = dinv[s] * w[i] * dinv[d];
        int b = d >> 2;
        int local = d & (NPB - 1);
        int p = atomicAdd(&bcur[b], 1);
        stage[p] = make_int2((local << 17) | s, __float_as_int(en));
    }
}

// phase B: one wave per bucket; 4 LDS cursors/wave; permute stage -> per-node CSR order
__launch_bounds__(256)
__global__ void k_placeB(const int2* __restrict__ stage, const int* __restrict__ row,
                         int2* __restrict__ edges) {
    __shared__ int cur[16];
    int wave = threadIdx.x >> 6;
    int lane = threadIdx.x & 63;
    int b = blockIdx.x * 4 + wave;   // bucket index, grid sized exactly NB/4
    int n0 = b << 2;
    if (lane < NPB) cur[wave * NPB + lane] = row[n0 + lane];
    __syncthreads();
    int lo = row[n0];
    int hi = row[n0 + NPB];
    for (int j = lo + lane; j < hi; j += 64) {
        int2 e = stage[j];
        int l = e.x >> 17;
        int p = atomicAdd(&cur[wave * NPB + l], 1);
        edges[p] = make_int2(e.x & 0x1FFFF, e.y);
    }
}

// ---------------- fp32 GEMM: H[nrows x 128] = X[nrows x 128] @ W[128 x 128] ----------------

#define GKT 16
#define GS 132

__launch_bounds__(256, 4)
__global__ void k_gemm(const float* __restrict__ X, const float* __restrict__ W,
                       float* __restrict__ H, int nrows) {
    __shared__ float As[GKT * GS];
    __shared__ float Bs[GKT * GS];
    int tid = threadIdx.x;
    int tx = tid & 15, ty = tid >> 4;
    int r0 = blockIdx.x * 128;
    float acc[8][8];
#pragma unroll
    for (int i = 0; i < 8; i++)
#pragma unroll
        for (int j = 0; j < 8; j++) acc[i][j] = 0.f;

    for (int k0 = 0; k0 < F; k0 += GKT) {
#pragma unroll
        for (int it = 0; it < 2; it++) {
            int f = tid + it * 256;
            int r = f >> 2;
            int kc = (f & 3) * 4;
            float4 v = make_float4(0.f, 0.f, 0.f, 0.f);
            if (r0 + r < nrows)
                v = *(const float4*)&X[(size_t)(r0 + r) * F + k0 + kc];
            As[(kc + 0) * GS + r] = v.x;
            As[(kc + 1) * GS + r] = v.y;
            As[(kc + 2) * GS + r] = v.z;
            As[(kc + 3) * GS + r] = v.w;
        }
#pragma unroll
        for (int it = 0; it < 2; it++) {
            int f = tid + it * 256;
            int kk = f >> 5;
            int cc = (f & 31) * 4;
            *(float4*)&Bs[kk * GS + cc] = *(const float4*)&W[(size_t)(k0 + kk) * F + cc];
        }
        __syncthreads();
#pragma unroll
        for (int kk = 0; kk < GKT; kk++) {
            float a[8], b[8];
            *(float4*)&a[0] = *(const float4*)&As[kk * GS + ty * 8];
            *(float4*)&a[4] = *(const float4*)&As[kk * GS + ty * 8 + 4];
            *(float4*)&b[0] = *(const float4*)&Bs[kk * GS + tx * 8];
            *(float4*)&b[4] = *(const float4*)&Bs[kk * GS + tx * 8 + 4];
#pragma unroll
            for (int i = 0; i < 8; i++)
#pragma unroll
                for (int j = 0; j < 8; j++)
                    acc[i][j] = fmaf(a[i], b[j], acc[i][j]);
        }
        __syncthreads();
    }
#pragma unroll
    for (int i = 0; i < 8; i++) {
        int r = r0 + ty * 8 + i;
        if (r < nrows) {
            *(float4*)&H[(size_t)r * F + tx * 8] = *(float4*)&acc[i][0];
            *(float4*)&H[(size_t)r * F + tx * 8 + 4] = *(float4*)&acc[i][4];
        }
    }
}

// ---------------- aggregation (packed int2 edges, 8 gathers in flight per wave) ----------------

__launch_bounds__(256)
__global__ void k_agg(const float* __restrict__ H, const int* __restrict__ row,
                      const int2* __restrict__ edges,
                      const float* __restrict__ dinv, const float* __restrict__ bias,
                      float* __restrict__ out, int n, int relu) {
    int node = blockIdx.x * 4 + (threadIdx.x >> 6);
    if (node >= n) return;
    int lane = threadIdx.x & 63;
    int half = lane >> 5;
    int sub = lane & 31;
    float4 acc = make_float4(0.f, 0.f, 0.f, 0.f);
    float4 acc2 = make_float4(0.f, 0.f, 0.f, 0.f);
    int beg = row[node], end = row[node + 1];
    int deg = end - beg;
    int t = half;
    // 4 edges per half-wave iteration (8 gathers in flight per wave)
    for (; t + 6 < deg; t += 8) {
        int2 e0 = edges[beg + t];
        int2 e1 = edges[beg + t + 2];
        int2 e2 = edges[beg + t + 4];
        int2 e3 = edges[beg + t + 6];
        float4 v0 = *(const float4*)&H[(size_t)e0.x * F + sub * 4];
        float4 v1 = *(const float4*)&H[(size_t)e1.x * F + sub * 4];
        float4 v2 = *(const float4*)&H[(size_t)e2.x * F + sub * 4];
        float4 v3 = *(const float4*)&H[(size_t)e3.x * F + sub * 4];
        float w0 = __int_as_float(e0.y), w1 = __int_as_float(e1.y);
        float w2 = __int_as_float(e2.y), w3 = __int_as_float(e3.y);
        acc.x = fmaf(w0, v0.x, acc.x);  acc.y = fmaf(w0, v0.y, acc.y);
        acc.z = fmaf(w0, v0.z, acc.z);  acc.w = fmaf(w0, v0.w, acc.w);
        acc2.x = fmaf(w1, v1.x, acc2.x); acc2.y = fmaf(w1, v1.y, acc2.y);
        acc2.z = fmaf(w1, v1.z, acc2.z); acc2.w = fmaf(w1, v1.w, acc2.w);
        acc.x = fmaf(w2, v2.x, acc.x);  acc.y = fmaf(w2, v2.y, acc.y);
        acc.z = fmaf(w2, v2.z, acc.z);  acc.w = fmaf(w2, v2.w, acc.w);
        acc2.x = fmaf(w3, v3.x, acc2.x); acc2.y = fmaf(w3, v3.y, acc2.y);
        acc2.z = fmaf(w3, v3.z, acc2.z); acc2.w = fmaf(w3, v3.w, acc2.w);
    }
    for (; t < deg; t += 2) {
        int2 e0 = edges[beg + t];
        float w0 = __int_as_float(e0.y);
        float4 v0 = *(const float4*)&H[(size_t)e0.x * F + sub * 4];
        acc.x = fmaf(w0, v0.x, acc.x);
        acc.y = fmaf(w0, v0.y, acc.y);
        acc.z = fmaf(w0, v0.z, acc.z);
        acc.w = fmaf(w0, v0.w, acc.w);
    }
    acc.x += acc2.x; acc.y += acc2.y; acc.z += acc2.z; acc.w += acc2.w;
    acc.x += __shfl_xor(acc.x, 32, 64);
    acc.y += __shfl_xor(acc.y, 32, 64);
    acc.z += __shfl_xor(acc.z, 32, 64);
    acc.w += __shfl_xor(acc.w, 32, 64);
    if (lane < 32) {
        float di = dinv[node];
        float sn = di * di;
        float4 h = *(const float4*)&H[(size_t)node * F + lane * 4];
        float4 b = *(const float4*)&bias[lane * 4];
        acc.x = fmaf(sn, h.x, acc.x) + b.x;
        acc.y = fmaf(sn, h.y, acc.y) + b.y;
        acc.z = fmaf(sn, h.z, acc.z) + b.z;
        acc.w = fmaf(sn, h.w, acc.w) + b.w;
        if (relu) {
            acc.x = fmaxf(acc.x, 0.f);
            acc.y = fmaxf(acc.y, 0.f);
            acc.z = fmaxf(acc.z, 0.f);
            acc.w = fmaxf(acc.w, 0.f);
        }
        *(float4*)&out[(size_t)node * F + lane * 4] = acc;
    }
}

// ---------------- final layer ----------------

__launch_bounds__(256)
__global__ void k_dot(const float* __restrict__ H, const float* __restrict__ Wf,
                      float* __restrict__ s, int n) {
    int node = blockIdx.x * 4 + (threadIdx.x >> 6);
    int lane = threadIdx.x & 63;
    if (node >= n) return;
    float2 h = *(const float2*)&H[(size_t)node * F + lane * 2];
    float2 w = *(const float2*)&Wf[lane * 2];
    float p = h.x * w.x + h.y * w.y;
    for (int off = 32; off; off >>= 1) p += __shfl_down(p, off, 64);
    if (lane == 0) s[node] = p;
}

__global__ void k_aggs(const float* __restrict__ s, const int* __restrict__ row,
                       const int2* __restrict__ edges,
                       const float* __restrict__ dinv, const float* __restrict__ bf,
                       float* __restrict__ out, int n) {
    int i = blockIdx.x * blockDim.x + threadIdx.x;
    if (i >= n) return;
    float di = dinv[i];
    float acc = di * di * s[i];
    int beg = row[i], end = row[i + 1];
    for (int j = beg; j < end; j++) {
        int2 e = edges[j];
        acc = fmaf(__int_as_float(e.y), s[e.x], acc);
    }
    out[i] = acc + bf[0];
}

// ---------------- host launch ----------------

extern "C" void kernel_launch(void* const* d_in, const int* in_sizes, int n_in,
                              void* d_out, int out_size, void* d_ws, size_t ws_size,
                              hipStream_t stream) {
    const float* x    = (const float*)d_in[0];
    const int*   ei   = (const int*)d_in[1];
    const float* ew   = (const float*)d_in[2];
    const float* Win  = (const float*)d_in[3];
    const float* bin  = (const float*)d_in[4];
    const float* Wmid = (const float*)d_in[5];
    const float* bmid = (const float*)d_in[6];
    const float* Wfin = (const float*)d_in[7];
    const float* bfin = (const float*)d_in[8];
    float* out = (float*)d_out;

    char* ws = (char*)d_ws;
    size_t off = 0;
    auto alloc = [&](size_t bytes) -> char* {
        char* p = ws + off;
        off = (off + bytes + 255) & ~(size_t)255;
        return p;
    };
    float* dinv  = (float*)alloc((size_t)N_NODES * 4);
    int*   row   = (int*)alloc((size_t)(N_NODES + 1) * 4);
    int*   pos   = (int*)alloc((size_t)N_NODES * 4);     // histogram / scan scratch
    int2*  edges = (int2*)alloc((size_t)N_EDGES * 8);    // final packed CSR
    int*   bcur  = (int*)alloc((size_t)NB * 4);
    int*   bsum  = (int*)alloc(128 * 4);
    float* ha    = (float*)alloc((size_t)N_NODES * F * 4);
    float* hb    = (float*)alloc((size_t)N_NODES * F * 4);
    int2*  stage = (int2*)ha;   // aliased: consumed by k_placeB before gemm1 writes ha
    float* sbuf  = ha;          // aliased: used after last gemm

    dim3 b256(256);
    int gN = (N_NODES + 255) / 256;
    int gE = (N_EDGES + 255) / 256;
    int gW = (N_NODES + 3) / 4;
    int gG = (N_NODES + 127) / 128;
    int gS = (N_NODES + 1023) / 1024;
    int gB = NB / 4;               // placeB: 4 buckets per 256-thread block

    hipLaunchKernelGGL(k_init, dim3(gN), b256, 0, stream, dinv, pos, N_NODES);
    hipLaunchKernelGGL(k_deg_hist, dim3(gE), b256, 0, stream, ei, ew, dinv, pos, N_EDGES);
    hipLaunchKernelGGL(k_dinv, dim3(gN), b256, 0, stream, dinv, N_NODES);
    hipLaunchKernelGGL(k_bsum, dim3(gS), b256, 0, stream, pos, bsum, N_NODES);
    hipLaunchKernelGGL(k_bscan, dim3(1), dim3(128), 0, stream, bsum, gS, &row[N_NODES]);
    hipLaunchKernelGGL(k_scan2, dim3(gS), b256, 0, stream, pos, bsum, row, bcur, N_NODES);
    hipLaunchKernelGGL(k_bucketA, dim3(gE), b256, 0, stream, ei, ew, dinv, bcur, stage, N_EDGES);
    hipLaunchKernelGGL(k_placeB, dim3(gB), b256, 0, stream, stage, row, edges);

    hipLaunchKernelGGL(k_gemm, dim3(gG), b256, 0, stream, x, Win, ha, N_NODES);
    hipLaunchKernelGGL(k_agg, dim3(gW), b256, 0, stream, ha, row, edges, dinv, bin, hb, N_NODES, 1);
    hipLaunchKernelGGL(k_gemm, dim3(gG), b256, 0, stream, hb, Wmid, ha, N_NODES);
    hipLaunchKernelGGL(k_agg, dim3(gW), b256, 0, stream, ha, row, edges, dinv, bmid, hb, N_NODES, 1);
    hipLaunchKernelGGL(k_gemm, dim3(gG), b256, 0, stream, hb, Wmid, ha, N_NODES);
    hipLaunchKernelGGL(k_agg, dim3(gW), b256, 0, stream, ha, row, edges, dinv, bmid, hb, N_NODES, 1);
    hipLaunchKernelGGL(k_dot, dim3(gW), b256, 0, stream, hb, Wfin, sbuf, N_NODES);
    hipLaunchKernelGGL(k_aggs, dim3(gN), b256, 0, stream, sbuf, row, edges, dinv, bfin, out, N_NODES);
}

// Round 6
// 802.624 us; speedup vs baseline: 1.4794x; 1.1128x over previous
//
#include <hip/hip_runtime.h>
#include <stdint.h>

#define N_NODES 100000
#define N_EDGES 1600000
#define F 128

// ---------------- XCD-privatized histogram (copy = blockIdx & 7) ----------------
// Device atomics execute in the owning XCD's L2; cross-XCD access migrates the
// line (~443 cyc + 64B fabric traffic, measured R4/R5). 8 private copies keep
// every atomic XCD-local under the round-robin block->XCD mapping (perf
// heuristic only; correctness holds regardless).

__global__ void k_zero(uint4* p, int n16) {
    int i = blockIdx.x * blockDim.x + threadIdx.x;
    if (i < n16) p[i] = make_uint4(0, 0, 0, 0);
}

// packed per-(copy,node) accumulator: high32 = edge count, low32 = sum(w * 2^24)
__global__ void k_hist8(const int* __restrict__ ei, const float* __restrict__ w,
                        unsigned long long* __restrict__ hist8, int e) {
    int i = blockIdx.x * blockDim.x + threadIdx.x;
    if (i < e) {
        int d = ei[N_EDGES + i];
        int c = blockIdx.x & 7;
        unsigned long long pack =
            (1ULL << 32) | (unsigned long long)(unsigned int)(w[i] * 16777216.0f);
        atomicAdd(&hist8[(size_t)c * N_NODES + d], pack);
    }
}

// sum 8 copies -> cnt (for scan) and deg -> dinv
__global__ void k_reduce(const unsigned long long* __restrict__ hist8,
                         float* __restrict__ dinv, int* __restrict__ cnt, int n) {
    int i = blockIdx.x * blockDim.x + threadIdx.x;
    if (i < n) {
        unsigned int c = 0;
        unsigned long long fx = 0;
#pragma unroll
        for (int k = 0; k < 8; k++) {
            unsigned long long v = hist8[(size_t)k * N_NODES + i];
            c += (unsigned int)(v >> 32);
            fx += (unsigned int)v;
        }
        float deg = 1.0f + (float)fx * (1.0f / 16777216.0f);
        dinv[i] = rsqrtf(deg);
        cnt[i] = (int)c;
    }
}

// ---------------- hierarchical exclusive scan ----------------
__launch_bounds__(256)
__global__ void k_bsum(const int* __restrict__ cnt, int* __restrict__ bsum, int n) {
    int b = blockIdx.x, tid = threadIdx.x;
    int base = b * 1024 + tid * 4;
    int s = 0;
#pragma unroll
    for (int j = 0; j < 4; j++)
        if (base + j < n) s += cnt[base + j];
    for (int off = 32; off; off >>= 1) s += __shfl_down(s, off, 64);
    __shared__ int ws[4];
    if ((tid & 63) == 0) ws[tid >> 6] = s;
    __syncthreads();
    if (tid == 0) bsum[b] = ws[0] + ws[1] + ws[2] + ws[3];
}

__launch_bounds__(128)
__global__ void k_bscan(int* bsum, int nb, int* row_last) {
    __shared__ int ls[128];
    int tid = threadIdx.x;
    int v = (tid < nb) ? bsum[tid] : 0;
    ls[tid] = v;
    __syncthreads();
    for (int off = 1; off < 128; off <<= 1) {
        int t = (tid >= off) ? ls[tid - off] : 0;
        __syncthreads();
        ls[tid] += t;
        __syncthreads();
    }
    int ex = tid ? ls[tid - 1] : 0;
    if (tid < nb) bsum[tid] = ex;
    if (tid == 0) *row_last = N_EDGES;
}

__launch_bounds__(256)
__global__ void k_scan2(int* __restrict__ cnt_pos, const int* __restrict__ boff,
                        int* __restrict__ row, int n) {
    __shared__ int ls[256];
    int b = blockIdx.x, tid = threadIdx.x;
    int base = b * 1024 + tid * 4;
    int v[4];
    int s = 0;
#pragma unroll
    for (int j = 0; j < 4; j++) {
        v[j] = (base + j < n) ? cnt_pos[base + j] : 0;
        s += v[j];
    }
    ls[tid] = s;
    __syncthreads();
    for (int off = 1; off < 256; off <<= 1) {
        int t = (tid >= off) ? ls[tid - off] : 0;
        __syncthreads();
        ls[tid] += t;
        __syncthreads();
    }
    int run = boff[b] + (tid ? ls[tid - 1] : 0);
#pragma unroll
    for (int j = 0; j < 4; j++) {
        int node = base + j;
        if (node < n) {
            row[node] = run;
            run += v[j];
        }
    }
}

// per-(copy,node) cursors: each copy owns a disjoint slice of the node's CSR segment
__global__ void k_cursor(const unsigned long long* __restrict__ hist8,
                         const int* __restrict__ row, int* __restrict__ cur8, int n) {
    int i = blockIdx.x * blockDim.x + threadIdx.x;
    if (i < n) {
        int run = row[i];
#pragma unroll
        for (int k = 0; k < 8; k++) {
            cur8[(size_t)k * N_NODES + i] = run;
            run += (int)(hist8[(size_t)k * N_NODES + i] >> 32);
        }
    }
}

// enorm inline + direct placement into final CSR (same grid geometry as k_hist8
// so edge i maps to the same copy c; segment order is irrelevant for a sum)
__global__ void k_place8(const int* __restrict__ ei, const float* __restrict__ w,
                         const float* __restrict__ dinv, int* __restrict__ cur8,
                         int2* __restrict__ edges, int e) {
    int i = blockIdx.x * blockDim.x + threadIdx.x;
    if (i < e) {
        int s = ei[i];
        int d = ei[N_EDGES + i];
        float en = dinv[s] * w[i] * dinv[d];
        int c = blockIdx.x & 7;
        int p = atomicAdd(&cur8[(size_t)c * N_NODES + d], 1);
        edges[p] = make_int2(s, __float_as_int(en));
    }
}

// ---------------- fp32 GEMM: H[nrows x 128] = X[nrows x 128] @ W[128 x 128] ----------------

#define GKT 16
#define GS 132

__launch_bounds__(256, 4)
__global__ void k_gemm(const float* __restrict__ X, const float* __restrict__ W,
                       float* __restrict__ H, int nrows) {
    __shared__ float As[GKT * GS];
    __shared__ float Bs[GKT * GS];
    int tid = threadIdx.x;
    int tx = tid & 15, ty = tid >> 4;
    int r0 = blockIdx.x * 128;
    float acc[8][8];
#pragma unroll
    for (int i = 0; i < 8; i++)
#pragma unroll
        for (int j = 0; j < 8; j++) acc[i][j] = 0.f;

    for (int k0 = 0; k0 < F; k0 += GKT) {
#pragma unroll
        for (int it = 0; it < 2; it++) {
            int f = tid + it * 256;
            int r = f >> 2;
            int kc = (f & 3) * 4;
            float4 v = make_float4(0.f, 0.f, 0.f, 0.f);
            if (r0 + r < nrows)
                v = *(const float4*)&X[(size_t)(r0 + r) * F + k0 + kc];
            As[(kc + 0) * GS + r] = v.x;
            As[(kc + 1) * GS + r] = v.y;
            As[(kc + 2) * GS + r] = v.z;
            As[(kc + 3) * GS + r] = v.w;
        }
#pragma unroll
        for (int it = 0; it < 2; it++) {
            int f = tid + it * 256;
            int kk = f >> 5;
            int cc = (f & 31) * 4;
            *(float4*)&Bs[kk * GS + cc] = *(const float4*)&W[(size_t)(k0 + kk) * F + cc];
        }
        __syncthreads();
#pragma unroll
        for (int kk = 0; kk < GKT; kk++) {
            float a[8], b[8];
            *(float4*)&a[0] = *(const float4*)&As[kk * GS + ty * 8];
            *(float4*)&a[4] = *(const float4*)&As[kk * GS + ty * 8 + 4];
            *(float4*)&b[0] = *(const float4*)&Bs[kk * GS + tx * 8];
            *(float4*)&b[4] = *(const float4*)&Bs[kk * GS + tx * 8 + 4];
#pragma unroll
            for (int i = 0; i < 8; i++)
#pragma unroll
                for (int j = 0; j < 8; j++)
                    acc[i][j] = fmaf(a[i], b[j], acc[i][j]);
        }
        __syncthreads();
    }
#pragma unroll
    for (int i = 0; i < 8; i++) {
        int r = r0 + ty * 8 + i;
        if (r < nrows) {
            *(float4*)&H[(size_t)r * F + tx * 8] = *(float4*)&acc[i][0];
            *(float4*)&H[(size_t)r * F + tx * 8 + 4] = *(float4*)&acc[i][4];
        }
    }
}

// ---------------- aggregation (packed int2 edges, 8 gathers in flight per wave) ----------------

__launch_bounds__(256)
__global__ void k_agg(const float* __restrict__ H, const int* __restrict__ row,
                      const int2* __restrict__ edges,
                      const float* __restrict__ dinv, const float* __restrict__ bias,
                      float* __restrict__ out, int n, int relu) {
    int node = blockIdx.x * 4 + (threadIdx.x >> 6);
    if (node >= n) return;
    int lane = threadIdx.x & 63;
    int half = lane >> 5;
    int sub = lane & 31;
    float4 acc = make_float4(0.f, 0.f, 0.f, 0.f);
    float4 acc2 = make_float4(0.f, 0.f, 0.f, 0.f);
    int beg = row[node], end = row[node + 1];
    int deg = end - beg;
    int t = half;
    for (; t + 6 < deg; t += 8) {
        int2 e0 = edges[beg + t];
        int2 e1 = edges[beg + t + 2];
        int2 e2 = edges[beg + t + 4];
        int2 e3 = edges[beg + t + 6];
        float4 v0 = *(const float4*)&H[(size_t)e0.x * F + sub * 4];
        float4 v1 = *(const float4*)&H[(size_t)e1.x * F + sub * 4];
        float4 v2 = *(const float4*)&H[(size_t)e2.x * F + sub * 4];
        float4 v3 = *(const float4*)&H[(size_t)e3.x * F + sub * 4];
        float w0 = __int_as_float(e0.y), w1 = __int_as_float(e1.y);
        float w2 = __int_as_float(e2.y), w3 = __int_as_float(e3.y);
        acc.x = fmaf(w0, v0.x, acc.x);  acc.y = fmaf(w0, v0.y, acc.y);
        acc.z = fmaf(w0, v0.z, acc.z);  acc.w = fmaf(w0, v0.w, acc.w);
        acc2.x = fmaf(w1, v1.x, acc2.x); acc2.y = fmaf(w1, v1.y, acc2.y);
        acc2.z = fmaf(w1, v1.z, acc2.z); acc2.w = fmaf(w1, v1.w, acc2.w);
        acc.x = fmaf(w2, v2.x, acc.x);  acc.y = fmaf(w2, v2.y, acc.y);
        acc.z = fmaf(w2, v2.z, acc.z);  acc.w = fmaf(w2, v2.w, acc.w);
        acc2.x = fmaf(w3, v3.x, acc2.x); acc2.y = fmaf(w3, v3.y, acc2.y);
        acc2.z = fmaf(w3, v3.z, acc2.z); acc2.w = fmaf(w3, v3.w, acc2.w);
    }
    for (; t < deg; t += 2) {
        int2 e0 = edges[beg + t];
        float w0 = __int_as_float(e0.y);
        float4 v0 = *(const float4*)&H[(size_t)e0.x * F + sub * 4];
        acc.x = fmaf(w0, v0.x, acc.x);
        acc.y = fmaf(w0, v0.y, acc.y);
        acc.z = fmaf(w0, v0.z, acc.z);
        acc.w = fmaf(w0, v0.w, acc.w);
    }
    acc.x += acc2.x; acc.y += acc2.y; acc.z += acc2.z; acc.w += acc2.w;
    acc.x += __shfl_xor(acc.x, 32, 64);
    acc.y += __shfl_xor(acc.y, 32, 64);
    acc.z += __shfl_xor(acc.z, 32, 64);
    acc.w += __shfl_xor(acc.w, 32, 64);
    if (lane < 32) {
        float di = dinv[node];
        float sn = di * di;
        float4 h = *(const float4*)&H[(size_t)node * F + lane * 4];
        float4 b = *(const float4*)&bias[lane * 4];
        acc.x = fmaf(sn, h.x, acc.x) + b.x;
        acc.y = fmaf(sn, h.y, acc.y) + b.y;
        acc.z = fmaf(sn, h.z, acc.z) + b.z;
        acc.w = fmaf(sn, h.w, acc.w) + b.w;
        if (relu) {
            acc.x = fmaxf(acc.x, 0.f);
            acc.y = fmaxf(acc.y, 0.f);
            acc.z = fmaxf(acc.z, 0.f);
            acc.w = fmaxf(acc.w, 0.f);
        }
        *(float4*)&out[(size_t)node * F + lane * 4] = acc;
    }
}

// ---------------- final layer ----------------

__launch_bounds__(256)
__global__ void k_dot(const float* __restrict__ H, const float* __restrict__ Wf,
                      float* __restrict__ s, int n) {
    int node = blockIdx.x * 4 + (threadIdx.x >> 6);
    int lane = threadIdx.x & 63;
    if (node >= n) return;
    float2 h = *(const float2*)&H[(size_t)node * F + lane * 2];
    float2 w = *(const float2*)&Wf[lane * 2];
    float p = h.x * w.x + h.y * w.y;
    for (int off = 32; off; off >>= 1) p += __shfl_down(p, off, 64);
    if (lane == 0) s[node] = p;
}

__global__ void k_aggs(const float* __restrict__ s, const int* __restrict__ row,
                       const int2* __restrict__ edges,
                       const float* __restrict__ dinv, const float* __restrict__ bf,
                       float* __restrict__ out, int n) {
    int i = blockIdx.x * blockDim.x + threadIdx.x;
    if (i >= n) return;
    float di = dinv[i];
    float acc = di * di * s[i];
    int beg = row[i], end = row[i + 1];
    for (int j = beg; j < end; j++) {
        int2 e = edges[j];
        acc = fmaf(__int_as_float(e.y), s[e.x], acc);
    }
    out[i] = acc + bf[0];
}

// ---------------- host launch ----------------

extern "C" void kernel_launch(void* const* d_in, const int* in_sizes, int n_in,
                              void* d_out, int out_size, void* d_ws, size_t ws_size,
                              hipStream_t stream) {
    const float* x    = (const float*)d_in[0];
    const int*   ei   = (const int*)d_in[1];
    const float* ew   = (const float*)d_in[2];
    const float* Win  = (const float*)d_in[3];
    const float* bin  = (const float*)d_in[4];
    const float* Wmid = (const float*)d_in[5];
    const float* bmid = (const float*)d_in[6];
    const float* Wfin = (const float*)d_in[7];
    const float* bfin = (const float*)d_in[8];
    float* out = (float*)d_out;

    char* ws = (char*)d_ws;
    size_t off = 0;
    auto alloc = [&](size_t bytes) -> char* {
        char* p = ws + off;
        off = (off + bytes + 255) & ~(size_t)255;
        return p;
    };
    float* dinv  = (float*)alloc((size_t)N_NODES * 4);
    int*   row   = (int*)alloc((size_t)(N_NODES + 1) * 4);
    int*   pos   = (int*)alloc((size_t)N_NODES * 4);     // histogram sum / scan scratch
    int2*  edges = (int2*)alloc((size_t)N_EDGES * 8);    // final packed CSR
    int*   bsum  = (int*)alloc(128 * 4);
    float* ha    = (float*)alloc((size_t)N_NODES * F * 4);
    float* hb    = (float*)alloc((size_t)N_NODES * F * 4);
    // aliased into ha (fully consumed before gemm1 writes ha):
    unsigned long long* hist8 = (unsigned long long*)ha;          // 6.4 MB
    int* cur8 = (int*)((char*)ha + (size_t)8 * N_NODES * 8);      // 3.2 MB
    float* sbuf = ha;  // aliased: used after last gemm

    dim3 b256(256);
    int gN = (N_NODES + 255) / 256;
    int gE = (N_EDGES + 255) / 256;
    int gW = (N_NODES + 3) / 4;
    int gG = (N_NODES + 127) / 128;
    int gS = (N_NODES + 1023) / 1024;
    int n16 = (int)(((size_t)8 * N_NODES * 8) / 16);   // hist8 bytes / 16
    int gZ = (n16 + 255) / 256;

    hipLaunchKernelGGL(k_zero, dim3(gZ), b256, 0, stream, (uint4*)hist8, n16);
    hipLaunchKernelGGL(k_hist8, dim3(gE), b256, 0, stream, ei, ew, hist8, N_EDGES);
    hipLaunchKernelGGL(k_reduce, dim3(gN), b256, 0, stream, hist8, dinv, pos, N_NODES);
    hipLaunchKernelGGL(k_bsum, dim3(gS), b256, 0, stream, pos, bsum, N_NODES);
    hipLaunchKernelGGL(k_bscan, dim3(1), dim3(128), 0, stream, bsum, gS, &row[N_NODES]);
    hipLaunchKernelGGL(k_scan2, dim3(gS), b256, 0, stream, pos, bsum, row, N_NODES);
    hipLaunchKernelGGL(k_cursor, dim3(gN), b256, 0, stream, hist8, row, cur8, N_NODES);
    hipLaunchKernelGGL(k_place8, dim3(gE), b256, 0, stream, ei, ew, dinv, cur8, edges, N_EDGES);

    hipLaunchKernelGGL(k_gemm, dim3(gG), b256, 0, stream, x, Win, ha, N_NODES);
    hipLaunchKernelGGL(k_agg, dim3(gW), b256, 0, stream, ha, row, edges, dinv, bin, hb, N_NODES, 1);
    hipLaunchKernelGGL(k_gemm, dim3(gG), b256, 0, stream, hb, Wmid, ha, N_NODES);
    hipLaunchKernelGGL(k_agg, dim3(gW), b256, 0, stream, ha, row, edges, dinv, bmid, hb, N_NODES, 1);
    hipLaunchKernelGGL(k_gemm, dim3(gG), b256, 0, stream, hb, Wmid, ha, N_NODES);
    hipLaunchKernelGGL(k_agg, dim3(gW), b256, 0, stream, ha, row, edges, dinv, bmid, hb, N_NODES, 1);
    hipLaunchKernelGGL(k_dot, dim3(gW), b256, 0, stream, hb, Wfin, sbuf, N_NODES);
    hipLaunchKernelGGL(k_aggs, dim3(gN), b256, 0, stream, sbuf, row, edges, dinv, bfin, out, N_NODES);
}

// Round 7
// 663.954 us; speedup vs baseline: 1.7884x; 1.2089x over previous
//
#include <hip/hip_runtime.h>
#include <stdint.h>

#define N_NODES 100000
#define N_EDGES 1600000
#define F 128

typedef _Float16 f16;
typedef _Float16 f16x4 __attribute__((ext_vector_type(4)));
typedef _Float16 f16x8 __attribute__((ext_vector_type(8)));

// ---------------- XCD-privatized histogram (copy = blockIdx & 7) ----------------
// Device atomics execute in the owning XCD's L2; cross-XCD access migrates the
// line (~443 cyc + 64B fabric, measured R4/R5). 8 private copies keep atomics
// XCD-local under round-robin block->XCD mapping (perf heuristic only).

__global__ void k_zero(uint4* p, int n16) {
    int i = blockIdx.x * blockDim.x + threadIdx.x;
    if (i < n16) p[i] = make_uint4(0, 0, 0, 0);
}

// packed per-(copy,node) accumulator: high32 = edge count, low32 = sum(w * 2^24)
__global__ void k_hist8(const int* __restrict__ ei, const float* __restrict__ w,
                        unsigned long long* __restrict__ hist8, int e) {
    int i = blockIdx.x * blockDim.x + threadIdx.x;
    if (i < e) {
        int d = ei[N_EDGES + i];
        int c = blockIdx.x & 7;
        unsigned long long pack =
            (1ULL << 32) | (unsigned long long)(unsigned int)(w[i] * 16777216.0f);
        atomicAdd(&hist8[(size_t)c * N_NODES + d], pack);
    }
}

__global__ void k_reduce(const unsigned long long* __restrict__ hist8,
                         float* __restrict__ dinv, int* __restrict__ cnt, int n) {
    int i = blockIdx.x * blockDim.x + threadIdx.x;
    if (i < n) {
        unsigned int c = 0;
        unsigned long long fx = 0;
#pragma unroll
        for (int k = 0; k < 8; k++) {
            unsigned long long v = hist8[(size_t)k * N_NODES + i];
            c += (unsigned int)(v >> 32);
            fx += (unsigned int)v;
        }
        float deg = 1.0f + (float)fx * (1.0f / 16777216.0f);
        dinv[i] = rsqrtf(deg);
        cnt[i] = (int)c;
    }
}

// ---------------- hierarchical exclusive scan ----------------
__launch_bounds__(256)
__global__ void k_bsum(const int* __restrict__ cnt, int* __restrict__ bsum, int n) {
    int b = blockIdx.x, tid = threadIdx.x;
    int base = b * 1024 + tid * 4;
    int s = 0;
#pragma unroll
    for (int j = 0; j < 4; j++)
        if (base + j < n) s += cnt[base + j];
    for (int off = 32; off; off >>= 1) s += __shfl_down(s, off, 64);
    __shared__ int ws[4];
    if ((tid & 63) == 0) ws[tid >> 6] = s;
    __syncthreads();
    if (tid == 0) bsum[b] = ws[0] + ws[1] + ws[2] + ws[3];
}

__launch_bounds__(128)
__global__ void k_bscan(int* bsum, int nb, int* row_last) {
    __shared__ int ls[128];
    int tid = threadIdx.x;
    int v = (tid < nb) ? bsum[tid] : 0;
    ls[tid] = v;
    __syncthreads();
    for (int off = 1; off < 128; off <<= 1) {
        int t = (tid >= off) ? ls[tid - off] : 0;
        __syncthreads();
        ls[tid] += t;
        __syncthreads();
    }
    int ex = tid ? ls[tid - 1] : 0;
    if (tid < nb) bsum[tid] = ex;
    if (tid == 0) *row_last = N_EDGES;
}

__launch_bounds__(256)
__global__ void k_scan2(int* __restrict__ cnt_pos, const int* __restrict__ boff,
                        int* __restrict__ row, int n) {
    __shared__ int ls[256];
    int b = blockIdx.x, tid = threadIdx.x;
    int base = b * 1024 + tid * 4;
    int v[4];
    int s = 0;
#pragma unroll
    for (int j = 0; j < 4; j++) {
        v[j] = (base + j < n) ? cnt_pos[base + j] : 0;
        s += v[j];
    }
    ls[tid] = s;
    __syncthreads();
    for (int off = 1; off < 256; off <<= 1) {
        int t = (tid >= off) ? ls[tid - off] : 0;
        __syncthreads();
        ls[tid] += t;
        __syncthreads();
    }
    int run = boff[b] + (tid ? ls[tid - 1] : 0);
#pragma unroll
    for (int j = 0; j < 4; j++) {
        int node = base + j;
        if (node < n) {
            row[node] = run;
            run += v[j];
        }
    }
}

__global__ void k_cursor(const unsigned long long* __restrict__ hist8,
                         const int* __restrict__ row, int* __restrict__ cur8, int n) {
    int i = blockIdx.x * blockDim.x + threadIdx.x;
    if (i < n) {
        int run = row[i];
#pragma unroll
        for (int k = 0; k < 8; k++) {
            cur8[(size_t)k * N_NODES + i] = run;
            run += (int)(hist8[(size_t)k * N_NODES + i] >> 32);
        }
    }
}

__global__ void k_place8(const int* __restrict__ ei, const float* __restrict__ w,
                         const float* __restrict__ dinv, int* __restrict__ cur8,
                         int2* __restrict__ edges, int e) {
    int i = blockIdx.x * blockDim.x + threadIdx.x;
    if (i < e) {
        int s = ei[i];
        int d = ei[N_EDGES + i];
        float en = dinv[s] * w[i] * dinv[d];
        int c = blockIdx.x & 7;
        int p = atomicAdd(&cur8[(size_t)c * N_NODES + d], 1);
        edges[p] = make_int2(s, __float_as_int(en));
    }
}

// ---------------- fp32 GEMM -> fp16 H16: H16[nrows x 128] = X @ W ----------------
// H is consumed only by k_agg (gather + self term); fp16 halves gather bytes.

#define GKT 16
#define GS 132

__launch_bounds__(256, 4)
__global__ void k_gemm(const float* __restrict__ X, const float* __restrict__ W,
                       f16* __restrict__ H16, int nrows) {
    __shared__ float As[GKT * GS];
    __shared__ float Bs[GKT * GS];
    int tid = threadIdx.x;
    int tx = tid & 15, ty = tid >> 4;
    int r0 = blockIdx.x * 128;
    float acc[8][8];
#pragma unroll
    for (int i = 0; i < 8; i++)
#pragma unroll
        for (int j = 0; j < 8; j++) acc[i][j] = 0.f;

    for (int k0 = 0; k0 < F; k0 += GKT) {
#pragma unroll
        for (int it = 0; it < 2; it++) {
            int f = tid + it * 256;
            int r = f >> 2;
            int kc = (f & 3) * 4;
            float4 v = make_float4(0.f, 0.f, 0.f, 0.f);
            if (r0 + r < nrows)
                v = *(const float4*)&X[(size_t)(r0 + r) * F + k0 + kc];
            As[(kc + 0) * GS + r] = v.x;
            As[(kc + 1) * GS + r] = v.y;
            As[(kc + 2) * GS + r] = v.z;
            As[(kc + 3) * GS + r] = v.w;
        }
#pragma unroll
        for (int it = 0; it < 2; it++) {
            int f = tid + it * 256;
            int kk = f >> 5;
            int cc = (f & 31) * 4;
            *(float4*)&Bs[kk * GS + cc] = *(const float4*)&W[(size_t)(k0 + kk) * F + cc];
        }
        __syncthreads();
#pragma unroll
        for (int kk = 0; kk < GKT; kk++) {
            float a[8], b[8];
            *(float4*)&a[0] = *(const float4*)&As[kk * GS + ty * 8];
            *(float4*)&a[4] = *(const float4*)&As[kk * GS + ty * 8 + 4];
            *(float4*)&b[0] = *(const float4*)&Bs[kk * GS + tx * 8];
            *(float4*)&b[4] = *(const float4*)&Bs[kk * GS + tx * 8 + 4];
#pragma unroll
            for (int i = 0; i < 8; i++)
#pragma unroll
                for (int j = 0; j < 8; j++)
                    acc[i][j] = fmaf(a[i], b[j], acc[i][j]);
        }
        __syncthreads();
    }
#pragma unroll
    for (int i = 0; i < 8; i++) {
        int r = r0 + ty * 8 + i;
        if (r < nrows) {
            f16x8 o;
#pragma unroll
            for (int j = 0; j < 8; j++) o[j] = (f16)acc[i][j];
            *(f16x8*)&H16[(size_t)r * F + tx * 8] = o;
        }
    }
}

// ---------------- aggregation: fp16 gather, fp32 accumulate ----------------
// one wave per node; half-wave (32 lanes x 4 halfs = 256B) covers one edge row;
// 4 edges per half-wave iteration -> 8 gathers in flight per wave

__launch_bounds__(256)
__global__ void k_agg(const f16* __restrict__ H16, const int* __restrict__ row,
                      const int2* __restrict__ edges,
                      const float* __restrict__ dinv, const float* __restrict__ bias,
                      float* __restrict__ out, int n, int relu) {
    int node = blockIdx.x * 4 + (threadIdx.x >> 6);
    if (node >= n) return;
    int lane = threadIdx.x & 63;
    int half = lane >> 5;
    int sub = lane & 31;
    float4 acc = make_float4(0.f, 0.f, 0.f, 0.f);
    float4 acc2 = make_float4(0.f, 0.f, 0.f, 0.f);
    int beg = row[node], end = row[node + 1];
    int deg = end - beg;
    int t = half;
    for (; t + 6 < deg; t += 8) {
        int2 e0 = edges[beg + t];
        int2 e1 = edges[beg + t + 2];
        int2 e2 = edges[beg + t + 4];
        int2 e3 = edges[beg + t + 6];
        f16x4 v0 = *(const f16x4*)&H16[(size_t)e0.x * F + sub * 4];
        f16x4 v1 = *(const f16x4*)&H16[(size_t)e1.x * F + sub * 4];
        f16x4 v2 = *(const f16x4*)&H16[(size_t)e2.x * F + sub * 4];
        f16x4 v3 = *(const f16x4*)&H16[(size_t)e3.x * F + sub * 4];
        float w0 = __int_as_float(e0.y), w1 = __int_as_float(e1.y);
        float w2 = __int_as_float(e2.y), w3 = __int_as_float(e3.y);
        acc.x = fmaf(w0, (float)v0[0], acc.x);  acc.y = fmaf(w0, (float)v0[1], acc.y);
        acc.z = fmaf(w0, (float)v0[2], acc.z);  acc.w = fmaf(w0, (float)v0[3], acc.w);
        acc2.x = fmaf(w1, (float)v1[0], acc2.x); acc2.y = fmaf(w1, (float)v1[1], acc2.y);
        acc2.z = fmaf(w1, (float)v1[2], acc2.z); acc2.w = fmaf(w1, (float)v1[3], acc2.w);
        acc.x = fmaf(w2, (float)v2[0], acc.x);  acc.y = fmaf(w2, (float)v2[1], acc.y);
        acc.z = fmaf(w2, (float)v2[2], acc.z);  acc.w = fmaf(w2, (float)v2[3], acc.w);
        acc2.x = fmaf(w3, (float)v3[0], acc2.x); acc2.y = fmaf(w3, (float)v3[1], acc2.y);
        acc2.z = fmaf(w3, (float)v3[2], acc2.z); acc2.w = fmaf(w3, (float)v3[3], acc2.w);
    }
    for (; t < deg; t += 2) {
        int2 e0 = edges[beg + t];
        float w0 = __int_as_float(e0.y);
        f16x4 v0 = *(const f16x4*)&H16[(size_t)e0.x * F + sub * 4];
        acc.x = fmaf(w0, (float)v0[0], acc.x);
        acc.y = fmaf(w0, (float)v0[1], acc.y);
        acc.z = fmaf(w0, (float)v0[2], acc.z);
        acc.w = fmaf(w0, (float)v0[3], acc.w);
    }
    acc.x += acc2.x; acc.y += acc2.y; acc.z += acc2.z; acc.w += acc2.w;
    acc.x += __shfl_xor(acc.x, 32, 64);
    acc.y += __shfl_xor(acc.y, 32, 64);
    acc.z += __shfl_xor(acc.z, 32, 64);
    acc.w += __shfl_xor(acc.w, 32, 64);
    if (lane < 32) {
        float di = dinv[node];
        float sn = di * di;
        f16x4 h = *(const f16x4*)&H16[(size_t)node * F + lane * 4];
        float4 b = *(const float4*)&bias[lane * 4];
        acc.x = fmaf(sn, (float)h[0], acc.x) + b.x;
        acc.y = fmaf(sn, (float)h[1], acc.y) + b.y;
        acc.z = fmaf(sn, (float)h[2], acc.z) + b.z;
        acc.w = fmaf(sn, (float)h[3], acc.w) + b.w;
        if (relu) {
            acc.x = fmaxf(acc.x, 0.f);
            acc.y = fmaxf(acc.y, 0.f);
            acc.z = fmaxf(acc.z, 0.f);
            acc.w = fmaxf(acc.w, 0.f);
        }
        *(float4*)&out[(size_t)node * F + lane * 4] = acc;
    }
}

// ---------------- final layer (fp32, reads agg output hb) ----------------

__launch_bounds__(256)
__global__ void k_dot(const float* __restrict__ H, const float* __restrict__ Wf,
                      float* __restrict__ s, int n) {
    int node = blockIdx.x * 4 + (threadIdx.x >> 6);
    int lane = threadIdx.x & 63;
    if (node >= n) return;
    float2 h = *(const float2*)&H[(size_t)node * F + lane * 2];
    float2 w = *(const float2*)&Wf[lane * 2];
    float p = h.x * w.x + h.y * w.y;
    for (int off = 32; off; off >>= 1) p += __shfl_down(p, off, 64);
    if (lane == 0) s[node] = p;
}

__global__ void k_aggs(const float* __restrict__ s, const int* __restrict__ row,
                       const int2* __restrict__ edges,
                       const float* __restrict__ dinv, const float* __restrict__ bf,
                       float* __restrict__ out, int n) {
    int i = blockIdx.x * blockDim.x + threadIdx.x;
    if (i >= n) return;
    float di = dinv[i];
    float acc = di * di * s[i];
    int beg = row[i], end = row[i + 1];
    for (int j = beg; j < end; j++) {
        int2 e = edges[j];
        acc = fmaf(__int_as_float(e.y), s[e.x], acc);
    }
    out[i] = acc + bf[0];
}

// ---------------- host launch ----------------

extern "C" void kernel_launch(void* const* d_in, const int* in_sizes, int n_in,
                              void* d_out, int out_size, void* d_ws, size_t ws_size,
                              hipStream_t stream) {
    const float* x    = (const float*)d_in[0];
    const int*   ei   = (const int*)d_in[1];
    const float* ew   = (const float*)d_in[2];
    const float* Win  = (const float*)d_in[3];
    const float* bin  = (const float*)d_in[4];
    const float* Wmid = (const float*)d_in[5];
    const float* bmid = (const float*)d_in[6];
    const float* Wfin = (const float*)d_in[7];
    const float* bfin = (const float*)d_in[8];
    float* out = (float*)d_out;

    char* ws = (char*)d_ws;
    size_t off = 0;
    auto alloc = [&](size_t bytes) -> char* {
        char* p = ws + off;
        off = (off + bytes + 255) & ~(size_t)255;
        return p;
    };
    float* dinv  = (float*)alloc((size_t)N_NODES * 4);
    int*   row   = (int*)alloc((size_t)(N_NODES + 1) * 4);
    int*   pos   = (int*)alloc((size_t)N_NODES * 4);
    int2*  edges = (int2*)alloc((size_t)N_EDGES * 8);
    int*   bsum  = (int*)alloc(128 * 4);
    f16*   h16   = (f16*)alloc((size_t)N_NODES * F * 2);   // 25.6 MB gemm output
    float* hb    = (float*)alloc((size_t)N_NODES * F * 4); // 51.2 MB agg output
    // aliased into h16 (consumed before gemm1 writes it):
    unsigned long long* hist8 = (unsigned long long*)h16;          // 6.4 MB
    int* cur8 = (int*)((char*)h16 + (size_t)8 * N_NODES * 8);      // 3.2 MB
    float* sbuf = (float*)h16;  // aliased: k_dot output, used after agg3

    dim3 b256(256);
    int gN = (N_NODES + 255) / 256;
    int gE = (N_EDGES + 255) / 256;
    int gW = (N_NODES + 3) / 4;
    int gG = (N_NODES + 127) / 128;
    int gS = (N_NODES + 1023) / 1024;
    int n16 = (int)(((size_t)8 * N_NODES * 8) / 16);
    int gZ = (n16 + 255) / 256;

    hipLaunchKernelGGL(k_zero, dim3(gZ), b256, 0, stream, (uint4*)hist8, n16);
    hipLaunchKernelGGL(k_hist8, dim3(gE), b256, 0, stream, ei, ew, hist8, N_EDGES);
    hipLaunchKernelGGL(k_reduce, dim3(gN), b256, 0, stream, hist8, dinv, pos, N_NODES);
    hipLaunchKernelGGL(k_bsum, dim3(gS), b256, 0, stream, pos, bsum, N_NODES);
    hipLaunchKernelGGL(k_bscan, dim3(1), dim3(128), 0, stream, bsum, gS, &row[N_NODES]);
    hipLaunchKernelGGL(k_scan2, dim3(gS), b256, 0, stream, pos, bsum, row, N_NODES);
    hipLaunchKernelGGL(k_cursor, dim3(gN), b256, 0, stream, hist8, row, cur8, N_NODES);
    hipLaunchKernelGGL(k_place8, dim3(gE), b256, 0, stream, ei, ew, dinv, cur8, edges, N_EDGES);

    hipLaunchKernelGGL(k_gemm, dim3(gG), b256, 0, stream, x, Win, h16, N_NODES);
    hipLaunchKernelGGL(k_agg, dim3(gW), b256, 0, stream, h16, row, edges, dinv, bin, hb, N_NODES, 1);
    hipLaunchKernelGGL(k_gemm, dim3(gG), b256, 0, stream, hb, Wmid, h16, N_NODES);
    hipLaunchKernelGGL(k_agg, dim3(gW), b256, 0, stream, h16, row, edges, dinv, bmid, hb, N_NODES, 1);
    hipLaunchKernelGGL(k_gemm, dim3(gG), b256, 0, stream, hb, Wmid, h16, N_NODES);
    hipLaunchKernelGGL(k_agg, dim3(gW), b256, 0, stream, h16, row, edges, dinv, bmid, hb, N_NODES, 1);
    hipLaunchKernelGGL(k_dot, dim3(gW), b256, 0, stream, hb, Wfin, sbuf, N_NODES);
    hipLaunchKernelGGL(k_aggs, dim3(gN), b256, 0, stream, sbuf, row, edges, dinv, bfin, out, N_NODES);
}

// Round 8
// 599.409 us; speedup vs baseline: 1.9810x; 1.1077x over previous
//
#include <hip/hip_runtime.h>
#include <stdint.h>

#define N_NODES 100000
#define N_EDGES 1600000
#define F 128

typedef _Float16 f16;
typedef _Float16 f16x2 __attribute__((ext_vector_type(2)));
typedef _Float16 f16x4 __attribute__((ext_vector_type(4)));
typedef _Float16 f16x8 __attribute__((ext_vector_type(8)));
typedef float f32x4 __attribute__((ext_vector_type(4)));

// ---------------- XCD-privatized histogram (copy = blockIdx & 7) ----------------

__global__ void k_zero(uint4* p, int n16) {
    int i = blockIdx.x * blockDim.x + threadIdx.x;
    if (i < n16) p[i] = make_uint4(0, 0, 0, 0);
}

__global__ void k_hist8(const int* __restrict__ ei, const float* __restrict__ w,
                        unsigned long long* __restrict__ hist8, int e) {
    int i = blockIdx.x * blockDim.x + threadIdx.x;
    if (i < e) {
        int d = ei[N_EDGES + i];
        int c = blockIdx.x & 7;
        unsigned long long pack =
            (1ULL << 32) | (unsigned long long)(unsigned int)(w[i] * 16777216.0f);
        atomicAdd(&hist8[(size_t)c * N_NODES + d], pack);
    }
}

__global__ void k_reduce(const unsigned long long* __restrict__ hist8,
                         float* __restrict__ dinv, int* __restrict__ cnt, int n) {
    int i = blockIdx.x * blockDim.x + threadIdx.x;
    if (i < n) {
        unsigned int c = 0;
        unsigned long long fx = 0;
#pragma unroll
        for (int k = 0; k < 8; k++) {
            unsigned long long v = hist8[(size_t)k * N_NODES + i];
            c += (unsigned int)(v >> 32);
            fx += (unsigned int)v;
        }
        float deg = 1.0f + (float)fx * (1.0f / 16777216.0f);
        dinv[i] = rsqrtf(deg);
        cnt[i] = (int)c;
    }
}

// ---------------- hierarchical exclusive scan ----------------
__launch_bounds__(256)
__global__ void k_bsum(const int* __restrict__ cnt, int* __restrict__ bsum, int n) {
    int b = blockIdx.x, tid = threadIdx.x;
    int base = b * 1024 + tid * 4;
    int s = 0;
#pragma unroll
    for (int j = 0; j < 4; j++)
        if (base + j < n) s += cnt[base + j];
    for (int off = 32; off; off >>= 1) s += __shfl_down(s, off, 64);
    __shared__ int ws[4];
    if ((tid & 63) == 0) ws[tid >> 6] = s;
    __syncthreads();
    if (tid == 0) bsum[b] = ws[0] + ws[1] + ws[2] + ws[3];
}

__launch_bounds__(128)
__global__ void k_bscan(int* bsum, int nb, int* row_last) {
    __shared__ int ls[128];
    int tid = threadIdx.x;
    int v = (tid < nb) ? bsum[tid] : 0;
    ls[tid] = v;
    __syncthreads();
    for (int off = 1; off < 128; off <<= 1) {
        int t = (tid >= off) ? ls[tid - off] : 0;
        __syncthreads();
        ls[tid] += t;
        __syncthreads();
    }
    int ex = tid ? ls[tid - 1] : 0;
    if (tid < nb) bsum[tid] = ex;
    if (tid == 0) *row_last = N_EDGES;
}

__launch_bounds__(256)
__global__ void k_scan2(int* __restrict__ cnt_pos, const int* __restrict__ boff,
                        int* __restrict__ row, int n) {
    __shared__ int ls[256];
    int b = blockIdx.x, tid = threadIdx.x;
    int base = b * 1024 + tid * 4;
    int v[4];
    int s = 0;
#pragma unroll
    for (int j = 0; j < 4; j++) {
        v[j] = (base + j < n) ? cnt_pos[base + j] : 0;
        s += v[j];
    }
    ls[tid] = s;
    __syncthreads();
    for (int off = 1; off < 256; off <<= 1) {
        int t = (tid >= off) ? ls[tid - off] : 0;
        __syncthreads();
        ls[tid] += t;
        __syncthreads();
    }
    int run = boff[b] + (tid ? ls[tid - 1] : 0);
#pragma unroll
    for (int j = 0; j < 4; j++) {
        int node = base + j;
        if (node < n) {
            row[node] = run;
            run += v[j];
        }
    }
}

__global__ void k_cursor(const unsigned long long* __restrict__ hist8,
                         const int* __restrict__ row, int* __restrict__ cur8, int n) {
    int i = blockIdx.x * blockDim.x + threadIdx.x;
    if (i < n) {
        int run = row[i];
#pragma unroll
        for (int k = 0; k < 8; k++) {
            cur8[(size_t)k * N_NODES + i] = run;
            run += (int)(hist8[(size_t)k * N_NODES + i] >> 32);
        }
    }
}

__global__ void k_place8(const int* __restrict__ ei, const float* __restrict__ w,
                         const float* __restrict__ dinv, int* __restrict__ cur8,
                         int2* __restrict__ edges, int e) {
    int i = blockIdx.x * blockDim.x + threadIdx.x;
    if (i < e) {
        int s = ei[i];
        int d = ei[N_EDGES + i];
        float en = dinv[s] * w[i] * dinv[d];
        int c = blockIdx.x & 7;
        int p = atomicAdd(&cur8[(size_t)c * N_NODES + d], 1);
        edges[p] = make_int2(s, __float_as_int(en));
    }
}

// ---------------- fp32 -> fp16 conversions (once per launch) ----------------

__global__ void k_cvt(const float* __restrict__ X, f16* __restrict__ Y, int n8) {
    int i = blockIdx.x * blockDim.x + threadIdx.x;
    if (i < n8) {
        float4 a = ((const float4*)X)[i * 2];
        float4 b = ((const float4*)X)[i * 2 + 1];
        f16x8 o;
        o[0] = (f16)a.x; o[1] = (f16)a.y; o[2] = (f16)a.z; o[3] = (f16)a.w;
        o[4] = (f16)b.x; o[5] = (f16)b.y; o[6] = (f16)b.z; o[7] = (f16)b.w;
        ((f16x8*)Y)[i] = o;
    }
}

// Wt[n][k] = W[k][n] as fp16 (B-operand wants per-column contiguous k)
__global__ void k_wt(const float* __restrict__ W, f16* __restrict__ Wt) {
    int t = threadIdx.x;
#pragma unroll
    for (int it = 0; it < 64; it++) {
        int idx = t + it * 256;
        int k = idx >> 7, n = idx & 127;
        Wt[n * 128 + k] = (f16)W[idx];
    }
}

// ---------------- fp16 MFMA GEMM: H[nrows x 128] = A[nrows x 128] @ W ----------------
// 4 waves x (32 rows x 128 cols); A-frags direct from global (no intra-block A reuse);
// Wt staged in LDS [128][136] (pad 8 -> 2-way bank alias = free).
// Layouts (m89/m120-verified): A[m=lane&15][k=quad*8+j], B[k=quad*8+j][n=lane&15],
// C/D: col=lane&15, row=quad*4+reg.

#define LDK 136

__launch_bounds__(256, 2)
__global__ void k_gemm16(const f16* __restrict__ A, const f16* __restrict__ Wt,
                         f16* __restrict__ H, int nrows) {
    __shared__ f16 Ws[128 * LDK];
    int tid = threadIdx.x;
    int r0 = blockIdx.x * 128;
    int wave = tid >> 6;
    int lane = tid & 63;
    int lrow = lane & 15;
    int quad = lane >> 4;

    // load A fragments from global: a[mt][kc] covers rows wave*32+mt*16+lrow, k=kc*32+quad*8
    f16x8 a[2][4];
#pragma unroll
    for (int mt = 0; mt < 2; mt++) {
        int row = r0 + wave * 32 + mt * 16 + lrow;
#pragma unroll
        for (int kc = 0; kc < 4; kc++) {
            if (row < nrows)
                a[mt][kc] = *(const f16x8*)&A[(size_t)row * F + kc * 32 + quad * 8];
            else
                a[mt][kc] = (f16x8){};
        }
    }
    // stage Wt into LDS (2048 16B-chunks / 256 threads = 8 each)
#pragma unroll
    for (int it = 0; it < 8; it++) {
        int c = tid + it * 256;
        int rw = c >> 4;
        int off = (c & 15) * 8;
        *(f16x8*)&Ws[rw * LDK + off] = *(const f16x8*)&Wt[rw * 128 + off];
    }
    __syncthreads();

    f32x4 acc[2][8] = {};
#pragma unroll
    for (int kc = 0; kc < 4; kc++) {
        f16x8 b[8];
#pragma unroll
        for (int nt = 0; nt < 8; nt++)
            b[nt] = *(const f16x8*)&Ws[(nt * 16 + lrow) * LDK + kc * 32 + quad * 8];
#pragma unroll
        for (int nt = 0; nt < 8; nt++) {
            acc[0][nt] = __builtin_amdgcn_mfma_f32_16x16x32_f16(a[0][kc], b[nt], acc[0][nt], 0, 0, 0);
            acc[1][nt] = __builtin_amdgcn_mfma_f32_16x16x32_f16(a[1][kc], b[nt], acc[1][nt], 0, 0, 0);
        }
    }
    // epilogue: row = wave*32 + mt*16 + quad*4 + r, col = nt*16 + lrow
#pragma unroll
    for (int mt = 0; mt < 2; mt++) {
#pragma unroll
        for (int r = 0; r < 4; r++) {
            int row = r0 + wave * 32 + mt * 16 + quad * 4 + r;
            if (row < nrows) {
#pragma unroll
                for (int nt = 0; nt < 8; nt++)
                    H[(size_t)row * F + nt * 16 + lrow] = (f16)acc[mt][nt][r];
            }
        }
    }
}

// ---------------- aggregation: fp16 gather, fp32 accumulate, fp16 out ----------------

__launch_bounds__(256)
__global__ void k_agg(const f16* __restrict__ H16, const int* __restrict__ row,
                      const int2* __restrict__ edges,
                      const float* __restrict__ dinv, const float* __restrict__ bias,
                      f16* __restrict__ out, int n) {
    int node = blockIdx.x * 4 + (threadIdx.x >> 6);
    if (node >= n) return;
    int lane = threadIdx.x & 63;
    int half = lane >> 5;
    int sub = lane & 31;
    float4 acc = make_float4(0.f, 0.f, 0.f, 0.f);
    float4 acc2 = make_float4(0.f, 0.f, 0.f, 0.f);
    int beg = row[node], end = row[node + 1];
    int deg = end - beg;
    int t = half;
    for (; t + 6 < deg; t += 8) {
        int2 e0 = edges[beg + t];
        int2 e1 = edges[beg + t + 2];
        int2 e2 = edges[beg + t + 4];
        int2 e3 = edges[beg + t + 6];
        f16x4 v0 = *(const f16x4*)&H16[(size_t)e0.x * F + sub * 4];
        f16x4 v1 = *(const f16x4*)&H16[(size_t)e1.x * F + sub * 4];
        f16x4 v2 = *(const f16x4*)&H16[(size_t)e2.x * F + sub * 4];
        f16x4 v3 = *(const f16x4*)&H16[(size_t)e3.x * F + sub * 4];
        float w0 = __int_as_float(e0.y), w1 = __int_as_float(e1.y);
        float w2 = __int_as_float(e2.y), w3 = __int_as_float(e3.y);
        acc.x = fmaf(w0, (float)v0[0], acc.x);  acc.y = fmaf(w0, (float)v0[1], acc.y);
        acc.z = fmaf(w0, (float)v0[2], acc.z);  acc.w = fmaf(w0, (float)v0[3], acc.w);
        acc2.x = fmaf(w1, (float)v1[0], acc2.x); acc2.y = fmaf(w1, (float)v1[1], acc2.y);
        acc2.z = fmaf(w1, (float)v1[2], acc2.z); acc2.w = fmaf(w1, (float)v1[3], acc2.w);
        acc.x = fmaf(w2, (float)v2[0], acc.x);  acc.y = fmaf(w2, (float)v2[1], acc.y);
        acc.z = fmaf(w2, (float)v2[2], acc.z);  acc.w = fmaf(w2, (float)v2[3], acc.w);
        acc2.x = fmaf(w3, (float)v3[0], acc2.x); acc2.y = fmaf(w3, (float)v3[1], acc2.y);
        acc2.z = fmaf(w3, (float)v3[2], acc2.z); acc2.w = fmaf(w3, (float)v3[3], acc2.w);
    }
    for (; t < deg; t += 2) {
        int2 e0 = edges[beg + t];
        float w0 = __int_as_float(e0.y);
        f16x4 v0 = *(const f16x4*)&H16[(size_t)e0.x * F + sub * 4];
        acc.x = fmaf(w0, (float)v0[0], acc.x);
        acc.y = fmaf(w0, (float)v0[1], acc.y);
        acc.z = fmaf(w0, (float)v0[2], acc.z);
        acc.w = fmaf(w0, (float)v0[3], acc.w);
    }
    acc.x += acc2.x; acc.y += acc2.y; acc.z += acc2.z; acc.w += acc2.w;
    acc.x += __shfl_xor(acc.x, 32, 64);
    acc.y += __shfl_xor(acc.y, 32, 64);
    acc.z += __shfl_xor(acc.z, 32, 64);
    acc.w += __shfl_xor(acc.w, 32, 64);
    if (lane < 32) {
        float di = dinv[node];
        float sn = di * di;
        f16x4 h = *(const f16x4*)&H16[(size_t)node * F + lane * 4];
        float4 b = *(const float4*)&bias[lane * 4];
        acc.x = fmaxf(fmaf(sn, (float)h[0], acc.x) + b.x, 0.f);
        acc.y = fmaxf(fmaf(sn, (float)h[1], acc.y) + b.y, 0.f);
        acc.z = fmaxf(fmaf(sn, (float)h[2], acc.z) + b.z, 0.f);
        acc.w = fmaxf(fmaf(sn, (float)h[3], acc.w) + b.w, 0.f);
        f16x4 o;
        o[0] = (f16)acc.x; o[1] = (f16)acc.y; o[2] = (f16)acc.z; o[3] = (f16)acc.w;
        *(f16x4*)&out[(size_t)node * F + lane * 4] = o;
    }
}

// ---------------- final layer ----------------

__launch_bounds__(256)
__global__ void k_dot(const f16* __restrict__ H, const float* __restrict__ Wf,
                      float* __restrict__ s, int n) {
    int node = blockIdx.x * 4 + (threadIdx.x >> 6);
    int lane = threadIdx.x & 63;
    if (node >= n) return;
    f16x2 h = *(const f16x2*)&H[(size_t)node * F + lane * 2];
    float2 w = *(const float2*)&Wf[lane * 2];
    float p = (float)h[0] * w.x + (float)h[1] * w.y;
    for (int off = 32; off; off >>= 1) p += __shfl_down(p, off, 64);
    if (lane == 0) s[node] = p;
}

__global__ void k_aggs(const float* __restrict__ s, const int* __restrict__ row,
                       const int2* __restrict__ edges,
                       const float* __restrict__ dinv, const float* __restrict__ bf,
                       float* __restrict__ out, int n) {
    int i = blockIdx.x * blockDim.x + threadIdx.x;
    if (i >= n) return;
    float di = dinv[i];
    float acc = di * di * s[i];
    int beg = row[i], end = row[i + 1];
    for (int j = beg; j < end; j++) {
        int2 e = edges[j];
        acc = fmaf(__int_as_float(e.y), s[e.x], acc);
    }
    out[i] = acc + bf[0];
}

// ---------------- host launch ----------------

extern "C" void kernel_launch(void* const* d_in, const int* in_sizes, int n_in,
                              void* d_out, int out_size, void* d_ws, size_t ws_size,
                              hipStream_t stream) {
    const float* x    = (const float*)d_in[0];
    const int*   ei   = (const int*)d_in[1];
    const float* ew   = (const float*)d_in[2];
    const float* Win  = (const float*)d_in[3];
    const float* bin  = (const float*)d_in[4];
    const float* Wmid = (const float*)d_in[5];
    const float* bmid = (const float*)d_in[6];
    const float* Wfin = (const float*)d_in[7];
    const float* bfin = (const float*)d_in[8];
    float* out = (float*)d_out;

    char* ws = (char*)d_ws;
    size_t off = 0;
    auto alloc = [&](size_t bytes) -> char* {
        char* p = ws + off;
        off = (off + bytes + 255) & ~(size_t)255;
        return p;
    };
    float* dinv  = (float*)alloc((size_t)N_NODES * 4);
    int*   row   = (int*)alloc((size_t)(N_NODES + 1) * 4);
    int*   pos   = (int*)alloc((size_t)N_NODES * 4);
    int2*  edges = (int2*)alloc((size_t)N_EDGES * 8);
    int*   bsum  = (int*)alloc(128 * 4);
    f16*   wtin  = (f16*)alloc(128 * 128 * 2);
    f16*   wtmid = (f16*)alloc(128 * 128 * 2);
    f16*   H16   = (f16*)alloc((size_t)N_NODES * F * 2);   // gemm out / agg in
    f16*   AB16  = (f16*)alloc((size_t)N_NODES * F * 2);   // x16 -> agg out chain
    // aliased into H16 (consumed before gemm1 writes it):
    unsigned long long* hist8 = (unsigned long long*)H16;          // 6.4 MB
    int* cur8 = (int*)((char*)H16 + (size_t)8 * N_NODES * 8);      // 3.2 MB
    float* sbuf = (float*)H16;  // aliased: k_dot out, H16 dead after agg3

    dim3 b256(256);
    int gN = (N_NODES + 255) / 256;
    int gE = (N_EDGES + 255) / 256;
    int gW = (N_NODES + 3) / 4;
    int gG = (N_NODES + 127) / 128;
    int gS = (N_NODES + 1023) / 1024;
    int n16 = (int)(((size_t)8 * N_NODES * 8) / 16);
    int gZ = (n16 + 255) / 256;
    int n8 = N_NODES * F / 8;
    int gC = (n8 + 255) / 256;

    hipLaunchKernelGGL(k_zero, dim3(gZ), b256, 0, stream, (uint4*)hist8, n16);
    hipLaunchKernelGGL(k_hist8, dim3(gE), b256, 0, stream, ei, ew, hist8, N_EDGES);
    hipLaunchKernelGGL(k_reduce, dim3(gN), b256, 0, stream, hist8, dinv, pos, N_NODES);
    hipLaunchKernelGGL(k_bsum, dim3(gS), b256, 0, stream, pos, bsum, N_NODES);
    hipLaunchKernelGGL(k_bscan, dim3(1), dim3(128), 0, stream, bsum, gS, &row[N_NODES]);
    hipLaunchKernelGGL(k_scan2, dim3(gS), b256, 0, stream, pos, bsum, row, N_NODES);
    hipLaunchKernelGGL(k_cursor, dim3(gN), b256, 0, stream, hist8, row, cur8, N_NODES);
    hipLaunchKernelGGL(k_place8, dim3(gE), b256, 0, stream, ei, ew, dinv, cur8, edges, N_EDGES);
    hipLaunchKernelGGL(k_cvt, dim3(gC), b256, 0, stream, x, AB16, n8);
    hipLaunchKernelGGL(k_wt, dim3(1), b256, 0, stream, Win, wtin);
    hipLaunchKernelGGL(k_wt, dim3(1), b256, 0, stream, Wmid, wtmid);

    hipLaunchKernelGGL(k_gemm16, dim3(gG), b256, 0, stream, AB16, wtin, H16, N_NODES);
    hipLaunchKernelGGL(k_agg, dim3(gW), b256, 0, stream, H16, row, edges, dinv, bin, AB16, N_NODES);
    hipLaunchKernelGGL(k_gemm16, dim3(gG), b256, 0, stream, AB16, wtmid, H16, N_NODES);
    hipLaunchKernelGGL(k_agg, dim3(gW), b256, 0, stream, H16, row, edges, dinv, bmid, AB16, N_NODES);
    hipLaunchKernelGGL(k_gemm16, dim3(gG), b256, 0, stream, AB16, wtmid, H16, N_NODES);
    hipLaunchKernelGGL(k_agg, dim3(gW), b256, 0, stream, H16, row, edges, dinv, bmid, AB16, N_NODES);
    hipLaunchKernelGGL(k_dot, dim3(gW), b256, 0, stream, AB16, Wfin, sbuf, N_NODES);
    hipLaunchKernelGGL(k_aggs, dim3(gN), b256, 0, stream, sbuf, row, edges, dinv, bfin, out, N_NODES);
}

// Round 9
// 597.761 us; speedup vs baseline: 1.9864x; 1.0028x over previous
//
#include <hip/hip_runtime.h>
#include <stdint.h>

#define N_NODES 100000
#define N_EDGES 1600000
#define F 128

typedef _Float16 f16;
typedef _Float16 f16x4 __attribute__((ext_vector_type(4)));
typedef _Float16 f16x8 __attribute__((ext_vector_type(8)));
typedef float f32x4 __attribute__((ext_vector_type(4)));

// edge pack: (src << 15) | (fp16 bits of w, sign bit dropped — w in [0,1))
__device__ inline float unpackw(unsigned int p) {
    unsigned short b = (unsigned short)(p & 0x7FFF);
    return (float)__builtin_bit_cast(f16, b);
}

// ---------------- XCD-privatized count histogram (copy = blockIdx & 7) ----------------
// Device atomics execute in the owning XCD's L2; cross-XCD access migrates the
// line (~443 cyc + 64B fabric, measured R4/R5). 8 private copies keep atomics
// XCD-local under round-robin block->XCD mapping (perf heuristic only).

__global__ void k_zero(uint4* p, int n16) {
    int i = blockIdx.x * blockDim.x + threadIdx.x;
    if (i < n16) p[i] = make_uint4(0, 0, 0, 0);
}

__global__ void k_hist8c(const int* __restrict__ ei, int* __restrict__ cnt8, int e) {
    int i = blockIdx.x * blockDim.x + threadIdx.x;
    if (i < e) {
        int d = ei[N_EDGES + i];
        int c = blockIdx.x & 7;
        atomicAdd(&cnt8[(size_t)c * N_NODES + d], 1);
    }
}

__global__ void k_reduce(const int* __restrict__ cnt8, int* __restrict__ cnt, int n) {
    int i = blockIdx.x * blockDim.x + threadIdx.x;
    if (i < n) {
        int c = 0;
#pragma unroll
        for (int k = 0; k < 8; k++) c += cnt8[(size_t)k * N_NODES + i];
        cnt[i] = c;
    }
}

// ---------------- hierarchical exclusive scan ----------------
__launch_bounds__(256)
__global__ void k_bsum(const int* __restrict__ cnt, int* __restrict__ bsum, int n) {
    int b = blockIdx.x, tid = threadIdx.x;
    int base = b * 1024 + tid * 4;
    int s = 0;
#pragma unroll
    for (int j = 0; j < 4; j++)
        if (base + j < n) s += cnt[base + j];
    for (int off = 32; off; off >>= 1) s += __shfl_down(s, off, 64);
    __shared__ int ws[4];
    if ((tid & 63) == 0) ws[tid >> 6] = s;
    __syncthreads();
    if (tid == 0) bsum[b] = ws[0] + ws[1] + ws[2] + ws[3];
}

__launch_bounds__(128)
__global__ void k_bscan(int* bsum, int nb, int* row_last) {
    __shared__ int ls[128];
    int tid = threadIdx.x;
    int v = (tid < nb) ? bsum[tid] : 0;
    ls[tid] = v;
    __syncthreads();
    for (int off = 1; off < 128; off <<= 1) {
        int t = (tid >= off) ? ls[tid - off] : 0;
        __syncthreads();
        ls[tid] += t;
        __syncthreads();
    }
    int ex = tid ? ls[tid - 1] : 0;
    if (tid < nb) bsum[tid] = ex;
    if (tid == 0) *row_last = N_EDGES;
}

__launch_bounds__(256)
__global__ void k_scan2(int* __restrict__ cnt_pos, const int* __restrict__ boff,
                        int* __restrict__ row, int n) {
    __shared__ int ls[256];
    int b = blockIdx.x, tid = threadIdx.x;
    int base = b * 1024 + tid * 4;
    int v[4];
    int s = 0;
#pragma unroll
    for (int j = 0; j < 4; j++) {
        v[j] = (base + j < n) ? cnt_pos[base + j] : 0;
        s += v[j];
    }
    ls[tid] = s;
    __syncthreads();
    for (int off = 1; off < 256; off <<= 1) {
        int t = (tid >= off) ? ls[tid - off] : 0;
        __syncthreads();
        ls[tid] += t;
        __syncthreads();
    }
    int run = boff[b] + (tid ? ls[tid - 1] : 0);
#pragma unroll
    for (int j = 0; j < 4; j++) {
        int node = base + j;
        if (node < n) {
            row[node] = run;
            run += v[j];
        }
    }
}

__global__ void k_cursor(const int* __restrict__ cnt8,
                         const int* __restrict__ row, int* __restrict__ cur8, int n) {
    int i = blockIdx.x * blockDim.x + threadIdx.x;
    if (i < n) {
        int run = row[i];
#pragma unroll
        for (int k = 0; k < 8; k++) {
            cur8[(size_t)k * N_NODES + i] = run;
            run += cnt8[(size_t)k * N_NODES + i];
        }
    }
}

// placement: no dinv dependency — short chain: (ei,ew) -> atomic -> 4B write
__global__ void k_place8(const int* __restrict__ ei, const float* __restrict__ w,
                         int* __restrict__ cur8, unsigned int* __restrict__ edges, int e) {
    int i = blockIdx.x * blockDim.x + threadIdx.x;
    if (i < e) {
        int s = ei[i];
        int d = ei[N_EDGES + i];
        int c = blockIdx.x & 7;
        int p = atomicAdd(&cur8[(size_t)c * N_NODES + d], 1);
        f16 hw = (f16)w[i];
        unsigned short b = __builtin_bit_cast(unsigned short, hw);
        edges[p] = ((unsigned int)s << 15) | (b & 0x7FFF);
    }
}

// deg from CSR (sequential stream, no atomics): deg = 1 + sum w
__global__ void k_deg(const unsigned int* __restrict__ edges, const int* __restrict__ row,
                      float* __restrict__ dinv, int n) {
    int i = blockIdx.x * blockDim.x + threadIdx.x;
    if (i >= n) return;
    float s = 1.0f;
    int beg = row[i], end = row[i + 1];
    for (int j = beg; j < end; j++) s += unpackw(edges[j]);
    dinv[i] = rsqrtf(s);
}

// ---------------- fp32 -> fp16 conversions ----------------

__global__ void k_cvt(const float* __restrict__ X, f16* __restrict__ Y, int n8) {
    int i = blockIdx.x * blockDim.x + threadIdx.x;
    if (i < n8) {
        float4 a = ((const float4*)X)[i * 2];
        float4 b = ((const float4*)X)[i * 2 + 1];
        f16x8 o;
        o[0] = (f16)a.x; o[1] = (f16)a.y; o[2] = (f16)a.z; o[3] = (f16)a.w;
        o[4] = (f16)b.x; o[5] = (f16)b.y; o[6] = (f16)b.z; o[7] = (f16)b.w;
        ((f16x8*)Y)[i] = o;
    }
}

__global__ void k_wt(const float* __restrict__ W, f16* __restrict__ Wt) {
    int t = threadIdx.x;
#pragma unroll
    for (int it = 0; it < 64; it++) {
        int idx = t + it * 256;
        int k = idx >> 7, n = idx & 127;
        Wt[n * 128 + k] = (f16)W[idx];
    }
}

// ---------------- fp16 MFMA GEMM with coalesced LDS epilogue ----------------
// Layouts (m89/m120-verified): A[m=lane&15][k=quad*8+j], B-as-A same, C/D: col=lane&15,
// row=quad*4+reg. Epilogue stages C via LDS (stride 132 f16) -> 16B coalesced stores.

#define LDK 136

__launch_bounds__(256, 2)
__global__ void k_gemm16(const f16* __restrict__ A, const f16* __restrict__ Wt,
                         f16* __restrict__ H, int nrows) {
    __shared__ f16 Ws[128 * LDK];
    int tid = threadIdx.x;
    int r0 = blockIdx.x * 128;
    int wave = tid >> 6;
    int lane = tid & 63;
    int lrow = lane & 15;
    int quad = lane >> 4;

    f16x8 a[2][4];
#pragma unroll
    for (int mt = 0; mt < 2; mt++) {
        int row = r0 + wave * 32 + mt * 16 + lrow;
#pragma unroll
        for (int kc = 0; kc < 4; kc++) {
            if (row < nrows)
                a[mt][kc] = *(const f16x8*)&A[(size_t)row * F + kc * 32 + quad * 8];
            else
                a[mt][kc] = (f16x8){};
        }
    }
#pragma unroll
    for (int it = 0; it < 8; it++) {
        int c = tid + it * 256;
        int rw = c >> 4;
        int off = (c & 15) * 8;
        *(f16x8*)&Ws[rw * LDK + off] = *(const f16x8*)&Wt[rw * 128 + off];
    }
    __syncthreads();

    f32x4 acc[2][8] = {};
#pragma unroll
    for (int kc = 0; kc < 4; kc++) {
        f16x8 b[8];
#pragma unroll
        for (int nt = 0; nt < 8; nt++)
            b[nt] = *(const f16x8*)&Ws[(nt * 16 + lrow) * LDK + kc * 32 + quad * 8];
#pragma unroll
        for (int nt = 0; nt < 8; nt++) {
            acc[0][nt] = __builtin_amdgcn_mfma_f32_16x16x32_f16(a[0][kc], b[nt], acc[0][nt], 0, 0, 0);
            acc[1][nt] = __builtin_amdgcn_mfma_f32_16x16x32_f16(a[1][kc], b[nt], acc[1][nt], 0, 0, 0);
        }
    }
    __syncthreads();  // Ws reads done; reuse as C staging [128][132]
#pragma unroll
    for (int mt = 0; mt < 2; mt++) {
#pragma unroll
        for (int r = 0; r < 4; r++) {
            int lr = wave * 32 + mt * 16 + quad * 4 + r;
#pragma unroll
            for (int nt = 0; nt < 8; nt++)
                Ws[lr * 132 + nt * 16 + lrow] = (f16)acc[mt][nt][r];
        }
    }
    __syncthreads();
#pragma unroll
    for (int it = 0; it < 8; it++) {
        int c = it * 256 + tid;       // 2048 chunks of 16B
        int rw = c >> 4;
        int col = (c & 15) * 8;
        int grow = r0 + rw;
        if (grow < nrows)
            *(f16x8*)&H[(size_t)grow * F + col] = *(const f16x8*)&Ws[rw * 132 + col];
    }
}

// ---------------- aggregation: deferred norm (dinv[src] broadcast gather) ----------------
// out_i = dd * sum_e( dinv[src]*w * h_src ) + dd^2 * h_i + b,  dd = dinv[i]

__launch_bounds__(256)
__global__ void k_agg(const f16* __restrict__ H16, const int* __restrict__ row,
                      const unsigned int* __restrict__ edges,
                      const float* __restrict__ dinv, const float* __restrict__ bias,
                      f16* __restrict__ out, int n) {
    int node = blockIdx.x * 4 + (threadIdx.x >> 6);
    if (node >= n) return;
    int lane = threadIdx.x & 63;
    int half = lane >> 5;
    int sub = lane & 31;
    float4 acc = make_float4(0.f, 0.f, 0.f, 0.f);
    float4 acc2 = make_float4(0.f, 0.f, 0.f, 0.f);
    int beg = row[node], end = row[node + 1];
    int deg = end - beg;
    int t = half;
    for (; t + 6 < deg; t += 8) {
        unsigned int e0 = edges[beg + t];
        unsigned int e1 = edges[beg + t + 2];
        unsigned int e2 = edges[beg + t + 4];
        unsigned int e3 = edges[beg + t + 6];
        int s0 = e0 >> 15, s1 = e1 >> 15, s2 = e2 >> 15, s3 = e3 >> 15;
        float w0 = unpackw(e0) * dinv[s0];
        float w1 = unpackw(e1) * dinv[s1];
        float w2 = unpackw(e2) * dinv[s2];
        float w3 = unpackw(e3) * dinv[s3];
        f16x4 v0 = *(const f16x4*)&H16[(size_t)s0 * F + sub * 4];
        f16x4 v1 = *(const f16x4*)&H16[(size_t)s1 * F + sub * 4];
        f16x4 v2 = *(const f16x4*)&H16[(size_t)s2 * F + sub * 4];
        f16x4 v3 = *(const f16x4*)&H16[(size_t)s3 * F + sub * 4];
        acc.x = fmaf(w0, (float)v0[0], acc.x);  acc.y = fmaf(w0, (float)v0[1], acc.y);
        acc.z = fmaf(w0, (float)v0[2], acc.z);  acc.w = fmaf(w0, (float)v0[3], acc.w);
        acc2.x = fmaf(w1, (float)v1[0], acc2.x); acc2.y = fmaf(w1, (float)v1[1], acc2.y);
        acc2.z = fmaf(w1, (float)v1[2], acc2.z); acc2.w = fmaf(w1, (float)v1[3], acc2.w);
        acc.x = fmaf(w2, (float)v2[0], acc.x);  acc.y = fmaf(w2, (float)v2[1], acc.y);
        acc.z = fmaf(w2, (float)v2[2], acc.z);  acc.w = fmaf(w2, (float)v2[3], acc.w);
        acc2.x = fmaf(w3, (float)v3[0], acc2.x); acc2.y = fmaf(w3, (float)v3[1], acc2.y);
        acc2.z = fmaf(w3, (float)v3[2], acc2.z); acc2.w = fmaf(w3, (float)v3[3], acc2.w);
    }
    for (; t < deg; t += 2) {
        unsigned int e0 = edges[beg + t];
        int s0 = e0 >> 15;
        float w0 = unpackw(e0) * dinv[s0];
        f16x4 v0 = *(const f16x4*)&H16[(size_t)s0 * F + sub * 4];
        acc.x = fmaf(w0, (float)v0[0], acc.x);
        acc.y = fmaf(w0, (float)v0[1], acc.y);
        acc.z = fmaf(w0, (float)v0[2], acc.z);
        acc.w = fmaf(w0, (float)v0[3], acc.w);
    }
    acc.x += acc2.x; acc.y += acc2.y; acc.z += acc2.z; acc.w += acc2.w;
    acc.x += __shfl_xor(acc.x, 32, 64);
    acc.y += __shfl_xor(acc.y, 32, 64);
    acc.z += __shfl_xor(acc.z, 32, 64);
    acc.w += __shfl_xor(acc.w, 32, 64);
    if (lane < 32) {
        float dd = dinv[node];
        float sn = dd * dd;
        f16x4 h = *(const f16x4*)&H16[(size_t)node * F + lane * 4];
        float4 b = *(const float4*)&bias[lane * 4];
        acc.x = fmaxf(fmaf(sn, (float)h[0], dd * acc.x) + b.x, 0.f);
        acc.y = fmaxf(fmaf(sn, (float)h[1], dd * acc.y) + b.y, 0.f);
        acc.z = fmaxf(fmaf(sn, (float)h[2], dd * acc.z) + b.z, 0.f);
        acc.w = fmaxf(fmaf(sn, (float)h[3], dd * acc.w) + b.w, 0.f);
        f16x4 o;
        o[0] = (f16)acc.x; o[1] = (f16)acc.y; o[2] = (f16)acc.z; o[3] = (f16)acc.w;
        *(f16x4*)&out[(size_t)node * F + lane * 4] = o;
    }
}

// agg3 fused with final dot: s[node] = relu(agg3)[:] . Wfin
__launch_bounds__(256)
__global__ void k_agg_dot(const f16* __restrict__ H16, const int* __restrict__ row,
                          const unsigned int* __restrict__ edges,
                          const float* __restrict__ dinv, const float* __restrict__ bias,
                          const float* __restrict__ Wf, float* __restrict__ sout, int n) {
    int node = blockIdx.x * 4 + (threadIdx.x >> 6);
    if (node >= n) return;
    int lane = threadIdx.x & 63;
    int half = lane >> 5;
    int sub = lane & 31;
    float4 acc = make_float4(0.f, 0.f, 0.f, 0.f);
    float4 acc2 = make_float4(0.f, 0.f, 0.f, 0.f);
    int beg = row[node], end = row[node + 1];
    int deg = end - beg;
    int t = half;
    for (; t + 6 < deg; t += 8) {
        unsigned int e0 = edges[beg + t];
        unsigned int e1 = edges[beg + t + 2];
        unsigned int e2 = edges[beg + t + 4];
        unsigned int e3 = edges[beg + t + 6];
        int s0 = e0 >> 15, s1 = e1 >> 15, s2 = e2 >> 15, s3 = e3 >> 15;
        float w0 = unpackw(e0) * dinv[s0];
        float w1 = unpackw(e1) * dinv[s1];
        float w2 = unpackw(e2) * dinv[s2];
        float w3 = unpackw(e3) * dinv[s3];
        f16x4 v0 = *(const f16x4*)&H16[(size_t)s0 * F + sub * 4];
        f16x4 v1 = *(const f16x4*)&H16[(size_t)s1 * F + sub * 4];
        f16x4 v2 = *(const f16x4*)&H16[(size_t)s2 * F + sub * 4];
        f16x4 v3 = *(const f16x4*)&H16[(size_t)s3 * F + sub * 4];
        acc.x = fmaf(w0, (float)v0[0], acc.x);  acc.y = fmaf(w0, (float)v0[1], acc.y);
        acc.z = fmaf(w0, (float)v0[2], acc.z);  acc.w = fmaf(w0, (float)v0[3], acc.w);
        acc2.x = fmaf(w1, (float)v1[0], acc2.x); acc2.y = fmaf(w1, (float)v1[1], acc2.y);
        acc2.z = fmaf(w1, (float)v1[2], acc2.z); acc2.w = fmaf(w1, (float)v1[3], acc2.w);
        acc.x = fmaf(w2, (float)v2[0], acc.x);  acc.y = fmaf(w2, (float)v2[1], acc.y);
        acc.z = fmaf(w2, (float)v2[2], acc.z);  acc.w = fmaf(w2, (float)v2[3], acc.w);
        acc2.x = fmaf(w3, (float)v3[0], acc2.x); acc2.y = fmaf(w3, (float)v3[1], acc2.y);
        acc2.z = fmaf(w3, (float)v3[2], acc2.z); acc2.w = fmaf(w3, (float)v3[3], acc2.w);
    }
    for (; t < deg; t += 2) {
        unsigned int e0 = edges[beg + t];
        int s0 = e0 >> 15;
        float w0 = unpackw(e0) * dinv[s0];
        f16x4 v0 = *(const f16x4*)&H16[(size_t)s0 * F + sub * 4];
        acc.x = fmaf(w0, (float)v0[0], acc.x);
        acc.y = fmaf(w0, (float)v0[1], acc.y);
        acc.z = fmaf(w0, (float)v0[2], acc.z);
        acc.w = fmaf(w0, (float)v0[3], acc.w);
    }
    acc.x += acc2.x; acc.y += acc2.y; acc.z += acc2.z; acc.w += acc2.w;
    acc.x += __shfl_xor(acc.x, 32, 64);
    acc.y += __shfl_xor(acc.y, 32, 64);
    acc.z += __shfl_xor(acc.z, 32, 64);
    acc.w += __shfl_xor(acc.w, 32, 64);
    if (lane < 32) {
        float dd = dinv[node];
        float sn = dd * dd;
        f16x4 h = *(const f16x4*)&H16[(size_t)node * F + lane * 4];
        float4 b = *(const float4*)&bias[lane * 4];
        float4 wf = *(const float4*)&Wf[lane * 4];
        float p = 0.f;
        p += fmaxf(fmaf(sn, (float)h[0], dd * acc.x) + b.x, 0.f) * wf.x;
        p += fmaxf(fmaf(sn, (float)h[1], dd * acc.y) + b.y, 0.f) * wf.y;
        p += fmaxf(fmaf(sn, (float)h[2], dd * acc.z) + b.z, 0.f) * wf.z;
        p += fmaxf(fmaf(sn, (float)h[3], dd * acc.w) + b.w, 0.f) * wf.w;
        p += __shfl_down(p, 16, 32);
        p += __shfl_down(p, 8, 32);
        p += __shfl_down(p, 4, 32);
        p += __shfl_down(p, 2, 32);
        p += __shfl_down(p, 1, 32);
        if (lane == 0) sout[node] = p;
    }
}

__global__ void k_aggs(const float* __restrict__ s, const int* __restrict__ row,
                       const unsigned int* __restrict__ edges,
                       const float* __restrict__ dinv, const float* __restrict__ bf,
                       float* __restrict__ out, int n) {
    int i = blockIdx.x * blockDim.x + threadIdx.x;
    if (i >= n) return;
    float dd = dinv[i];
    float ae = 0.f;
    int beg = row[i], end = row[i + 1];
    for (int j = beg; j < end; j++) {
        unsigned int p = edges[j];
        int src = p >> 15;
        ae = fmaf(unpackw(p) * dinv[src], s[src], ae);
    }
    out[i] = fmaf(dd, ae, dd * dd * s[i]) + bf[0];
}

// ---------------- host launch ----------------

extern "C" void kernel_launch(void* const* d_in, const int* in_sizes, int n_in,
                              void* d_out, int out_size, void* d_ws, size_t ws_size,
                              hipStream_t stream) {
    const float* x    = (const float*)d_in[0];
    const int*   ei   = (const int*)d_in[1];
    const float* ew   = (const float*)d_in[2];
    const float* Win  = (const float*)d_in[3];
    const float* bin  = (const float*)d_in[4];
    const float* Wmid = (const float*)d_in[5];
    const float* bmid = (const float*)d_in[6];
    const float* Wfin = (const float*)d_in[7];
    const float* bfin = (const float*)d_in[8];
    float* out = (float*)d_out;

    char* ws = (char*)d_ws;
    size_t off = 0;
    auto alloc = [&](size_t bytes) -> char* {
        char* p = ws + off;
        off = (off + bytes + 255) & ~(size_t)255;
        return p;
    };
    float* dinv  = (float*)alloc((size_t)N_NODES * 4);
    int*   row   = (int*)alloc((size_t)(N_NODES + 1) * 4);
    int*   pos   = (int*)alloc((size_t)N_NODES * 4);
    unsigned int* edges = (unsigned int*)alloc((size_t)N_EDGES * 4);  // packed 4B CSR
    int*   bsum  = (int*)alloc(128 * 4);
    f16*   wtin  = (f16*)alloc(128 * 128 * 2);
    f16*   wtmid = (f16*)alloc(128 * 128 * 2);
    f16*   H16   = (f16*)alloc((size_t)N_NODES * F * 2);   // gemm out / agg in
    f16*   AB16  = (f16*)alloc((size_t)N_NODES * F * 2);   // x16 -> agg out chain
    // aliased into H16 (consumed before gemm1 writes it):
    int* cnt8 = (int*)H16;                                  // 3.2 MB
    int* cur8 = (int*)((char*)H16 + (size_t)8 * N_NODES * 4); // 3.2 MB
    // s buffer aliases AB16 (consumed by gemm3 before agg_dot writes it)
    float* sbuf = (float*)AB16;

    dim3 b256(256);
    int gN = (N_NODES + 255) / 256;
    int gE = (N_EDGES + 255) / 256;
    int gW = (N_NODES + 3) / 4;
    int gG = (N_NODES + 127) / 128;
    int gS = (N_NODES + 1023) / 1024;
    int n16 = (int)(((size_t)8 * N_NODES * 4) / 16);  // cnt8 bytes / 16
    int gZ = (n16 + 255) / 256;
    int n8 = N_NODES * F / 8;
    int gC = (n8 + 255) / 256;

    hipLaunchKernelGGL(k_zero, dim3(gZ), b256, 0, stream, (uint4*)cnt8, n16);
    hipLaunchKernelGGL(k_hist8c, dim3(gE), b256, 0, stream, ei, cnt8, N_EDGES);
    hipLaunchKernelGGL(k_reduce, dim3(gN), b256, 0, stream, cnt8, pos, N_NODES);
    hipLaunchKernelGGL(k_bsum, dim3(gS), b256, 0, stream, pos, bsum, N_NODES);
    hipLaunchKernelGGL(k_bscan, dim3(1), dim3(128), 0, stream, bsum, gS, &row[N_NODES]);
    hipLaunchKernelGGL(k_scan2, dim3(gS), b256, 0, stream, pos, bsum, row, N_NODES);
    hipLaunchKernelGGL(k_cursor, dim3(gN), b256, 0, stream, cnt8, row, cur8, N_NODES);
    hipLaunchKernelGGL(k_place8, dim3(gE), b256, 0, stream, ei, ew, cur8, edges, N_EDGES);
    hipLaunchKernelGGL(k_deg, dim3(gN), b256, 0, stream, edges, row, dinv, N_NODES);
    hipLaunchKernelGGL(k_cvt, dim3(gC), b256, 0, stream, x, AB16, n8);
    hipLaunchKernelGGL(k_wt, dim3(1), b256, 0, stream, Win, wtin);
    hipLaunchKernelGGL(k_wt, dim3(1), b256, 0, stream, Wmid, wtmid);

    hipLaunchKernelGGL(k_gemm16, dim3(gG), b256, 0, stream, AB16, wtin, H16, N_NODES);
    hipLaunchKernelGGL(k_agg, dim3(gW), b256, 0, stream, H16, row, edges, dinv, bin, AB16, N_NODES);
    hipLaunchKernelGGL(k_gemm16, dim3(gG), b256, 0, stream, AB16, wtmid, H16, N_NODES);
    hipLaunchKernelGGL(k_agg, dim3(gW), b256, 0, stream, H16, row, edges, dinv, bmid, AB16, N_NODES);
    hipLaunchKernelGGL(k_gemm16, dim3(gG), b256, 0, stream, AB16, wtmid, H16, N_NODES);
    hipLaunchKernelGGL(k_agg_dot, dim3(gW), b256, 0, stream, H16, row, edges, dinv, bmid, Wfin, sbuf, N_NODES);
    hipLaunchKernelGGL(k_aggs, dim3(gN), b256, 0, stream, sbuf, row, edges, dinv, bfin, out, N_NODES);
}

// Round 10
// 568.495 us; speedup vs baseline: 2.0887x; 1.0515x over previous
//
#include <hip/hip_runtime.h>
#include <stdint.h>

#define N_NODES 100000
#define N_EDGES 1600000
#define F 128
#define NPBK 16                   // nodes per bucket
#define NBK (N_NODES / NPBK)      // 6250 buckets (exact)

typedef _Float16 f16;
typedef _Float16 f16x4 __attribute__((ext_vector_type(4)));
typedef _Float16 f16x8 __attribute__((ext_vector_type(8)));
typedef float f32x4 __attribute__((ext_vector_type(4)));

// edge pack: (src << 15) | (fp16 bits of w, sign bit dropped — w in [0,1))
__device__ inline float unpackw(unsigned int p) {
    unsigned short b = (unsigned short)(p & 0x7FFF);
    return (float)__builtin_bit_cast(f16, b);
}

// ---------------- XCD-privatized count histogram (copy = blockIdx & 7) ----------------
// Measured R9: a cross-XCD scattered write costs one 64B line migration+writeback
// regardless of payload (WRITE_SIZE == writes*64B). All structures below keep each
// cache line owned by a single XCD (copy c written only by blocks with blockIdx&7==c).

__global__ void k_zero(uint4* p, int n16) {
    int i = blockIdx.x * blockDim.x + threadIdx.x;
    if (i < n16) p[i] = make_uint4(0, 0, 0, 0);
}

__global__ void k_hist8c(const int* __restrict__ ei, int* __restrict__ cnt8, int e) {
    int i = blockIdx.x * blockDim.x + threadIdx.x;
    if (i < e) {
        int d = ei[N_EDGES + i];
        int c = blockIdx.x & 7;
        atomicAdd(&cnt8[(size_t)c * N_NODES + d], 1);
    }
}

__global__ void k_reduce(const int* __restrict__ cnt8, int* __restrict__ cnt, int n) {
    int i = blockIdx.x * blockDim.x + threadIdx.x;
    if (i < n) {
        int c = 0;
#pragma unroll
        for (int k = 0; k < 8; k++) c += cnt8[(size_t)k * N_NODES + i];
        cnt[i] = c;
    }
}

// ---------------- hierarchical exclusive scan ----------------
__launch_bounds__(256)
__global__ void k_bsum(const int* __restrict__ cnt, int* __restrict__ bsum, int n) {
    int b = blockIdx.x, tid = threadIdx.x;
    int base = b * 1024 + tid * 4;
    int s = 0;
#pragma unroll
    for (int j = 0; j < 4; j++)
        if (base + j < n) s += cnt[base + j];
    for (int off = 32; off; off >>= 1) s += __shfl_down(s, off, 64);
    __shared__ int ws[4];
    if ((tid & 63) == 0) ws[tid >> 6] = s;
    __syncthreads();
    if (tid == 0) bsum[b] = ws[0] + ws[1] + ws[2] + ws[3];
}

__launch_bounds__(128)
__global__ void k_bscan(int* bsum, int nb, int* row_last) {
    __shared__ int ls[128];
    int tid = threadIdx.x;
    int v = (tid < nb) ? bsum[tid] : 0;
    ls[tid] = v;
    __syncthreads();
    for (int off = 1; off < 128; off <<= 1) {
        int t = (tid >= off) ? ls[tid - off] : 0;
        __syncthreads();
        ls[tid] += t;
        __syncthreads();
    }
    int ex = tid ? ls[tid - 1] : 0;
    if (tid < nb) bsum[tid] = ex;
    if (tid == 0) *row_last = N_EDGES;
}

__launch_bounds__(256)
__global__ void k_scan2(int* __restrict__ cnt_pos, const int* __restrict__ boff,
                        int* __restrict__ row, int n) {
    __shared__ int ls[256];
    int b = blockIdx.x, tid = threadIdx.x;
    int base = b * 1024 + tid * 4;
    int v[4];
    int s = 0;
#pragma unroll
    for (int j = 0; j < 4; j++) {
        v[j] = (base + j < n) ? cnt_pos[base + j] : 0;
        s += v[j];
    }
    ls[tid] = s;
    __syncthreads();
    for (int off = 1; off < 256; off <<= 1) {
        int t = (tid >= off) ? ls[tid - off] : 0;
        __syncthreads();
        ls[tid] += t;
        __syncthreads();
    }
    int run = boff[b] + (tid ? ls[tid - 1] : 0);
#pragma unroll
    for (int j = 0; j < 4; j++) {
        int node = base + j;
        if (node < n) {
            row[node] = run;
            run += v[j];
        }
    }
}

// (copy,bucket) stage cursors: bucket segment = CSR range, subdivided by copy
__global__ void k_bucketcur(const int* __restrict__ cnt8, const int* __restrict__ row,
                            int* __restrict__ cur8b) {
    int b = blockIdx.x * blockDim.x + threadIdx.x;
    if (b >= NBK) return;
    int n0 = b * NPBK;
    int run = row[n0];
#pragma unroll
    for (int c = 0; c < 8; c++) {
        cur8b[(size_t)c * NBK + b] = run;
        int s = 0;
#pragma unroll
        for (int j = 0; j < NPBK; j++) s += cnt8[(size_t)c * N_NODES + n0 + j];
        run += s;
    }
}

// phase A: append to XCD-private (copy,bucket) slice — dense, migration-free frontier
__global__ void k_placeA(const int* __restrict__ ei, const float* __restrict__ w,
                         int* __restrict__ cur8b, int2* __restrict__ stage, int e) {
    int i = blockIdx.x * blockDim.x + threadIdx.x;
    if (i < e) {
        int s = ei[i];
        int d = ei[N_EDGES + i];
        int c = blockIdx.x & 7;
        int b = d >> 4;
        int local = d & (NPBK - 1);
        int p = atomicAdd(&cur8b[(size_t)c * NBK + b], 1);
        stage[p] = make_int2((local << 17) | s, __float_as_int(w[i]));
    }
}

// phase B: one wave per bucket; sequential stage read, dense 1-2KB final write window
__launch_bounds__(256)
__global__ void k_placeB(const int2* __restrict__ stage, const int* __restrict__ row,
                         unsigned int* __restrict__ edges) {
    __shared__ int cur[4 * NPBK];
    int wave = threadIdx.x >> 6;
    int lane = threadIdx.x & 63;
    int b = blockIdx.x * 4 + wave;
    if (b >= NBK) return;
    int n0 = b * NPBK;
    if (lane < NPBK) cur[wave * NPBK + lane] = row[n0 + lane];
    __syncthreads();
    int lo = row[n0];
    int hi = row[n0 + NPBK];
    for (int j = lo + lane; j < hi; j += 64) {
        int2 rec = stage[j];
        int l = rec.x >> 17;
        int src = rec.x & 0x1FFFF;
        f16 hw = (f16)__int_as_float(rec.y);
        unsigned short wb = __builtin_bit_cast(unsigned short, hw);
        int p = atomicAdd(&cur[wave * NPBK + l], 1);
        edges[p] = ((unsigned int)src << 15) | (wb & 0x7FFF);
    }
}

// deg from CSR (sequential stream, no atomics): deg = 1 + sum w
__global__ void k_deg(const unsigned int* __restrict__ edges, const int* __restrict__ row,
                      float* __restrict__ dinv, int n) {
    int i = blockIdx.x * blockDim.x + threadIdx.x;
    if (i >= n) return;
    float s = 1.0f;
    int beg = row[i], end = row[i + 1];
    for (int j = beg; j < end; j++) s += unpackw(edges[j]);
    dinv[i] = rsqrtf(s);
}

// ---------------- fp32 -> fp16 conversions ----------------

__global__ void k_cvt(const float* __restrict__ X, f16* __restrict__ Y, int n8) {
    int i = blockIdx.x * blockDim.x + threadIdx.x;
    if (i < n8) {
        float4 a = ((const float4*)X)[i * 2];
        float4 b = ((const float4*)X)[i * 2 + 1];
        f16x8 o;
        o[0] = (f16)a.x; o[1] = (f16)a.y; o[2] = (f16)a.z; o[3] = (f16)a.w;
        o[4] = (f16)b.x; o[5] = (f16)b.y; o[6] = (f16)b.z; o[7] = (f16)b.w;
        ((f16x8*)Y)[i] = o;
    }
}

__global__ void k_wt(const float* __restrict__ W, f16* __restrict__ Wt) {
    int t = threadIdx.x;
#pragma unroll
    for (int it = 0; it < 64; it++) {
        int idx = t + it * 256;
        int k = idx >> 7, n = idx & 127;
        Wt[n * 128 + k] = (f16)W[idx];
    }
}

// ---------------- fp16 MFMA GEMM with coalesced LDS epilogue ----------------

#define LDK 136

__launch_bounds__(256, 2)
__global__ void k_gemm16(const f16* __restrict__ A, const f16* __restrict__ Wt,
                         f16* __restrict__ H, int nrows) {
    __shared__ f16 Ws[128 * LDK];
    int tid = threadIdx.x;
    int r0 = blockIdx.x * 128;
    int wave = tid >> 6;
    int lane = tid & 63;
    int lrow = lane & 15;
    int quad = lane >> 4;

    f16x8 a[2][4];
#pragma unroll
    for (int mt = 0; mt < 2; mt++) {
        int row = r0 + wave * 32 + mt * 16 + lrow;
#pragma unroll
        for (int kc = 0; kc < 4; kc++) {
            if (row < nrows)
                a[mt][kc] = *(const f16x8*)&A[(size_t)row * F + kc * 32 + quad * 8];
            else
                a[mt][kc] = (f16x8){};
        }
    }
#pragma unroll
    for (int it = 0; it < 8; it++) {
        int c = tid + it * 256;
        int rw = c >> 4;
        int off = (c & 15) * 8;
        *(f16x8*)&Ws[rw * LDK + off] = *(const f16x8*)&Wt[rw * 128 + off];
    }
    __syncthreads();

    f32x4 acc[2][8] = {};
#pragma unroll
    for (int kc = 0; kc < 4; kc++) {
        f16x8 b[8];
#pragma unroll
        for (int nt = 0; nt < 8; nt++)
            b[nt] = *(const f16x8*)&Ws[(nt * 16 + lrow) * LDK + kc * 32 + quad * 8];
#pragma unroll
        for (int nt = 0; nt < 8; nt++) {
            acc[0][nt] = __builtin_amdgcn_mfma_f32_16x16x32_f16(a[0][kc], b[nt], acc[0][nt], 0, 0, 0);
            acc[1][nt] = __builtin_amdgcn_mfma_f32_16x16x32_f16(a[1][kc], b[nt], acc[1][nt], 0, 0, 0);
        }
    }
    __syncthreads();
#pragma unroll
    for (int mt = 0; mt < 2; mt++) {
#pragma unroll
        for (int r = 0; r < 4; r++) {
            int lr = wave * 32 + mt * 16 + quad * 4 + r;
#pragma unroll
            for (int nt = 0; nt < 8; nt++)
                Ws[lr * 132 + nt * 16 + lrow] = (f16)acc[mt][nt][r];
        }
    }
    __syncthreads();
#pragma unroll
    for (int it = 0; it < 8; it++) {
        int c = it * 256 + tid;
        int rw = c >> 4;
        int col = (c & 15) * 8;
        int grow = r0 + rw;
        if (grow < nrows)
            *(f16x8*)&H[(size_t)grow * F + col] = *(const f16x8*)&Ws[rw * 132 + col];
    }
}

// ---------------- aggregation: deferred norm (dinv[src] broadcast gather) ----------------

__launch_bounds__(256)
__global__ void k_agg(const f16* __restrict__ H16, const int* __restrict__ row,
                      const unsigned int* __restrict__ edges,
                      const float* __restrict__ dinv, const float* __restrict__ bias,
                      f16* __restrict__ out, int n) {
    int node = blockIdx.x * 4 + (threadIdx.x >> 6);
    if (node >= n) return;
    int lane = threadIdx.x & 63;
    int half = lane >> 5;
    int sub = lane & 31;
    float4 acc = make_float4(0.f, 0.f, 0.f, 0.f);
    float4 acc2 = make_float4(0.f, 0.f, 0.f, 0.f);
    int beg = row[node], end = row[node + 1];
    int deg = end - beg;
    int t = half;
    for (; t + 6 < deg; t += 8) {
        unsigned int e0 = edges[beg + t];
        unsigned int e1 = edges[beg + t + 2];
        unsigned int e2 = edges[beg + t + 4];
        unsigned int e3 = edges[beg + t + 6];
        int s0 = e0 >> 15, s1 = e1 >> 15, s2 = e2 >> 15, s3 = e3 >> 15;
        float w0 = unpackw(e0) * dinv[s0];
        float w1 = unpackw(e1) * dinv[s1];
        float w2 = unpackw(e2) * dinv[s2];
        float w3 = unpackw(e3) * dinv[s3];
        f16x4 v0 = *(const f16x4*)&H16[(size_t)s0 * F + sub * 4];
        f16x4 v1 = *(const f16x4*)&H16[(size_t)s1 * F + sub * 4];
        f16x4 v2 = *(const f16x4*)&H16[(size_t)s2 * F + sub * 4];
        f16x4 v3 = *(const f16x4*)&H16[(size_t)s3 * F + sub * 4];
        acc.x = fmaf(w0, (float)v0[0], acc.x);  acc.y = fmaf(w0, (float)v0[1], acc.y);
        acc.z = fmaf(w0, (float)v0[2], acc.z);  acc.w = fmaf(w0, (float)v0[3], acc.w);
        acc2.x = fmaf(w1, (float)v1[0], acc2.x); acc2.y = fmaf(w1, (float)v1[1], acc2.y);
        acc2.z = fmaf(w1, (float)v1[2], acc2.z); acc2.w = fmaf(w1, (float)v1[3], acc2.w);
        acc.x = fmaf(w2, (float)v2[0], acc.x);  acc.y = fmaf(w2, (float)v2[1], acc.y);
        acc.z = fmaf(w2, (float)v2[2], acc.z);  acc.w = fmaf(w2, (float)v2[3], acc.w);
        acc2.x = fmaf(w3, (float)v3[0], acc2.x); acc2.y = fmaf(w3, (float)v3[1], acc2.y);
        acc2.z = fmaf(w3, (float)v3[2], acc2.z); acc2.w = fmaf(w3, (float)v3[3], acc2.w);
    }
    for (; t < deg; t += 2) {
        unsigned int e0 = edges[beg + t];
        int s0 = e0 >> 15;
        float w0 = unpackw(e0) * dinv[s0];
        f16x4 v0 = *(const f16x4*)&H16[(size_t)s0 * F + sub * 4];
        acc.x = fmaf(w0, (float)v0[0], acc.x);
        acc.y = fmaf(w0, (float)v0[1], acc.y);
        acc.z = fmaf(w0, (float)v0[2], acc.z);
        acc.w = fmaf(w0, (float)v0[3], acc.w);
    }
    acc.x += acc2.x; acc.y += acc2.y; acc.z += acc2.z; acc.w += acc2.w;
    acc.x += __shfl_xor(acc.x, 32, 64);
    acc.y += __shfl_xor(acc.y, 32, 64);
    acc.z += __shfl_xor(acc.z, 32, 64);
    acc.w += __shfl_xor(acc.w, 32, 64);
    if (lane < 32) {
        float dd = dinv[node];
        float sn = dd * dd;
        f16x4 h = *(const f16x4*)&H16[(size_t)node * F + lane * 4];
        float4 b = *(const float4*)&bias[lane * 4];
        acc.x = fmaxf(fmaf(sn, (float)h[0], dd * acc.x) + b.x, 0.f);
        acc.y = fmaxf(fmaf(sn, (float)h[1], dd * acc.y) + b.y, 0.f);
        acc.z = fmaxf(fmaf(sn, (float)h[2], dd * acc.z) + b.z, 0.f);
        acc.w = fmaxf(fmaf(sn, (float)h[3], dd * acc.w) + b.w, 0.f);
        f16x4 o;
        o[0] = (f16)acc.x; o[1] = (f16)acc.y; o[2] = (f16)acc.z; o[3] = (f16)acc.w;
        *(f16x4*)&out[(size_t)node * F + lane * 4] = o;
    }
}

// agg3 fused with final dot: s[node] = relu(agg3)[:] . Wfin
__launch_bounds__(256)
__global__ void k_agg_dot(const f16* __restrict__ H16, const int* __restrict__ row,
                          const unsigned int* __restrict__ edges,
                          const float* __restrict__ dinv, const float* __restrict__ bias,
                          const float* __restrict__ Wf, float* __restrict__ sout, int n) {
    int node = blockIdx.x * 4 + (threadIdx.x >> 6);
    if (node >= n) return;
    int lane = threadIdx.x & 63;
    int half = lane >> 5;
    int sub = lane & 31;
    float4 acc = make_float4(0.f, 0.f, 0.f, 0.f);
    float4 acc2 = make_float4(0.f, 0.f, 0.f, 0.f);
    int beg = row[node], end = row[node + 1];
    int deg = end - beg;
    int t = half;
    for (; t + 6 < deg; t += 8) {
        unsigned int e0 = edges[beg + t];
        unsigned int e1 = edges[beg + t + 2];
        unsigned int e2 = edges[beg + t + 4];
        unsigned int e3 = edges[beg + t + 6];
        int s0 = e0 >> 15, s1 = e1 >> 15, s2 = e2 >> 15, s3 = e3 >> 15;
        float w0 = unpackw(e0) * dinv[s0];
        float w1 = unpackw(e1) * dinv[s1];
        float w2 = unpackw(e2) * dinv[s2];
        float w3 = unpackw(e3) * dinv[s3];
        f16x4 v0 = *(const f16x4*)&H16[(size_t)s0 * F + sub * 4];
        f16x4 v1 = *(const f16x4*)&H16[(size_t)s1 * F + sub * 4];
        f16x4 v2 = *(const f16x4*)&H16[(size_t)s2 * F + sub * 4];
        f16x4 v3 = *(const f16x4*)&H16[(size_t)s3 * F + sub * 4];
        acc.x = fmaf(w0, (float)v0[0], acc.x);  acc.y = fmaf(w0, (float)v0[1], acc.y);
        acc.z = fmaf(w0, (float)v0[2], acc.z);  acc.w = fmaf(w0, (float)v0[3], acc.w);
        acc2.x = fmaf(w1, (float)v1[0], acc2.x); acc2.y = fmaf(w1, (float)v1[1], acc2.y);
        acc2.z = fmaf(w1, (float)v1[2], acc2.z); acc2.w = fmaf(w1, (float)v1[3], acc2.w);
        acc.x = fmaf(w2, (float)v2[0], acc.x);  acc.y = fmaf(w2, (float)v2[1], acc.y);
        acc.z = fmaf(w2, (float)v2[2], acc.z);  acc.w = fmaf(w2, (float)v2[3], acc.w);
        acc2.x = fmaf(w3, (float)v3[0], acc2.x); acc2.y = fmaf(w3, (float)v3[1], acc2.y);
        acc2.z = fmaf(w3, (float)v3[2], acc2.z); acc2.w = fmaf(w3, (float)v3[3], acc2.w);
    }
    for (; t < deg; t += 2) {
        unsigned int e0 = edges[beg + t];
        int s0 = e0 >> 15;
        float w0 = unpackw(e0) * dinv[s0];
        f16x4 v0 = *(const f16x4*)&H16[(size_t)s0 * F + sub * 4];
        acc.x = fmaf(w0, (float)v0[0], acc.x);
        acc.y = fmaf(w0, (float)v0[1], acc.y);
        acc.z = fmaf(w0, (float)v0[2], acc.z);
        acc.w = fmaf(w0, (float)v0[3], acc.w);
    }
    acc.x += acc2.x; acc.y += acc2.y; acc.z += acc2.z; acc.w += acc2.w;
    acc.x += __shfl_xor(acc.x, 32, 64);
    acc.y += __shfl_xor(acc.y, 32, 64);
    acc.z += __shfl_xor(acc.z, 32, 64);
    acc.w += __shfl_xor(acc.w, 32, 64);
    if (lane < 32) {
        float dd = dinv[node];
        float sn = dd * dd;
        f16x4 h = *(const f16x4*)&H16[(size_t)node * F + lane * 4];
        float4 b = *(const float4*)&bias[lane * 4];
        float4 wf = *(const float4*)&Wf[lane * 4];
        float p = 0.f;
        p += fmaxf(fmaf(sn, (float)h[0], dd * acc.x) + b.x, 0.f) * wf.x;
        p += fmaxf(fmaf(sn, (float)h[1], dd * acc.y) + b.y, 0.f) * wf.y;
        p += fmaxf(fmaf(sn, (float)h[2], dd * acc.z) + b.z, 0.f) * wf.z;
        p += fmaxf(fmaf(sn, (float)h[3], dd * acc.w) + b.w, 0.f) * wf.w;
        p += __shfl_down(p, 16, 32);
        p += __shfl_down(p, 8, 32);
        p += __shfl_down(p, 4, 32);
        p += __shfl_down(p, 2, 32);
        p += __shfl_down(p, 1, 32);
        if (lane == 0) sout[node] = p;
    }
}

__global__ void k_aggs(const float* __restrict__ s, const int* __restrict__ row,
                       const unsigned int* __restrict__ edges,
                       const float* __restrict__ dinv, const float* __restrict__ bf,
                       float* __restrict__ out, int n) {
    int i = blockIdx.x * blockDim.x + threadIdx.x;
    if (i >= n) return;
    float dd = dinv[i];
    float ae = 0.f;
    int beg = row[i], end = row[i + 1];
    for (int j = beg; j < end; j++) {
        unsigned int p = edges[j];
        int src = p >> 15;
        ae = fmaf(unpackw(p) * dinv[src], s[src], ae);
    }
    out[i] = fmaf(dd, ae, dd * dd * s[i]) + bf[0];
}

// ---------------- host launch ----------------

extern "C" void kernel_launch(void* const* d_in, const int* in_sizes, int n_in,
                              void* d_out, int out_size, void* d_ws, size_t ws_size,
                              hipStream_t stream) {
    const float* x    = (const float*)d_in[0];
    const int*   ei   = (const int*)d_in[1];
    const float* ew   = (const float*)d_in[2];
    const float* Win  = (const float*)d_in[3];
    const float* bin  = (const float*)d_in[4];
    const float* Wmid = (const float*)d_in[5];
    const float* bmid = (const float*)d_in[6];
    const float* Wfin = (const float*)d_in[7];
    const float* bfin = (const float*)d_in[8];
    float* out = (float*)d_out;

    char* ws = (char*)d_ws;
    size_t off = 0;
    auto alloc = [&](size_t bytes) -> char* {
        char* p = ws + off;
        off = (off + bytes + 255) & ~(size_t)255;
        return p;
    };
    float* dinv  = (float*)alloc((size_t)N_NODES * 4);
    int*   row   = (int*)alloc((size_t)(N_NODES + 1) * 4);
    int*   pos   = (int*)alloc((size_t)N_NODES * 4);
    unsigned int* edges = (unsigned int*)alloc((size_t)N_EDGES * 4);  // packed 4B CSR
    int*   bsum  = (int*)alloc(128 * 4);
    f16*   wtin  = (f16*)alloc(128 * 128 * 2);
    f16*   wtmid = (f16*)alloc(128 * 128 * 2);
    f16*   H16   = (f16*)alloc((size_t)N_NODES * F * 2);   // gemm out / agg in
    f16*   AB16  = (f16*)alloc((size_t)N_NODES * F * 2);   // x16 -> agg out chain
    // aliased into H16's 25.6MB (all consumed before gemm1 writes H16):
    int*  cnt8  = (int*)H16;                                      // 3.2 MB
    int*  cur8b = (int*)((char*)H16 + (size_t)8 * N_NODES * 4);   // 0.2 MB
    int2* stage = (int2*)((char*)H16 + (size_t)8 * N_NODES * 4 + (size_t)8 * NBK * 4 + 256);
    float* sbuf = (float*)AB16;  // aliased: consumed by gemm3 before agg_dot writes

    dim3 b256(256);
    int gN = (N_NODES + 255) / 256;
    int gE = (N_EDGES + 255) / 256;
    int gW = (N_NODES + 3) / 4;
    int gG = (N_NODES + 127) / 128;
    int gS = (N_NODES + 1023) / 1024;
    int n16 = (int)(((size_t)8 * N_NODES * 4) / 16);
    int gZ = (n16 + 255) / 256;
    int n8 = N_NODES * F / 8;
    int gC = (n8 + 255) / 256;
    int gBC = (NBK + 255) / 256;
    int gPB = (NBK + 3) / 4;

    hipLaunchKernelGGL(k_zero, dim3(gZ), b256, 0, stream, (uint4*)cnt8, n16);
    hipLaunchKernelGGL(k_hist8c, dim3(gE), b256, 0, stream, ei, cnt8, N_EDGES);
    hipLaunchKernelGGL(k_reduce, dim3(gN), b256, 0, stream, cnt8, pos, N_NODES);
    hipLaunchKernelGGL(k_bsum, dim3(gS), b256, 0, stream, pos, bsum, N_NODES);
    hipLaunchKernelGGL(k_bscan, dim3(1), dim3(128), 0, stream, bsum, gS, &row[N_NODES]);
    hipLaunchKernelGGL(k_scan2, dim3(gS), b256, 0, stream, pos, bsum, row, N_NODES);
    hipLaunchKernelGGL(k_bucketcur, dim3(gBC), b256, 0, stream, cnt8, row, cur8b);
    hipLaunchKernelGGL(k_placeA, dim3(gE), b256, 0, stream, ei, ew, cur8b, stage, N_EDGES);
    hipLaunchKernelGGL(k_placeB, dim3(gPB), b256, 0, stream, stage, row, edges);
    hipLaunchKernelGGL(k_deg, dim3(gN), b256, 0, stream, edges, row, dinv, N_NODES);
    hipLaunchKernelGGL(k_cvt, dim3(gC), b256, 0, stream, x, AB16, n8);
    hipLaunchKernelGGL(k_wt, dim3(1), b256, 0, stream, Win, wtin);
    hipLaunchKernelGGL(k_wt, dim3(1), b256, 0, stream, Wmid, wtmid);

    hipLaunchKernelGGL(k_gemm16, dim3(gG), b256, 0, stream, AB16, wtin, H16, N_NODES);
    hipLaunchKernelGGL(k_agg, dim3(gW), b256, 0, stream, H16, row, edges, dinv, bin, AB16, N_NODES);
    hipLaunchKernelGGL(k_gemm16, dim3(gG), b256, 0, stream, AB16, wtmid, H16, N_NODES);
    hipLaunchKernelGGL(k_agg, dim3(gW), b256, 0, stream, H16, row, edges, dinv, bmid, AB16, N_NODES);
    hipLaunchKernelGGL(k_gemm16, dim3(gG), b256, 0, stream, AB16, wtmid, H16, N_NODES);
    hipLaunchKernelGGL(k_agg_dot, dim3(gW), b256, 0, stream, H16, row, edges, dinv, bmid, Wfin, sbuf, N_NODES);
    hipLaunchKernelGGL(k_aggs, dim3(gN), b256, 0, stream, sbuf, row, edges, dinv, bfin, out, N_NODES);
}

// Round 11
// 546.970 us; speedup vs baseline: 2.1709x; 1.0394x over previous
//
#include <hip/hip_runtime.h>
#include <stdint.h>

#define N_NODES 100000
#define N_EDGES 1600000
#define F 128
#define NPBK 16                   // nodes per bucket
#define NBK (N_NODES / NPBK)      // 6250 buckets (exact)

typedef _Float16 f16;
typedef _Float16 f16x4 __attribute__((ext_vector_type(4)));
typedef _Float16 f16x8 __attribute__((ext_vector_type(8)));
typedef float f32x4 __attribute__((ext_vector_type(4)));

// edge pack: (src << 15) | (fp16 bits of w, sign bit dropped — w in [0,1))
__device__ inline float unpackw(unsigned int p) {
    unsigned short b = (unsigned short)(p & 0x7FFF);
    return (float)__builtin_bit_cast(f16, b);
}

// ---------------- XCD-privatized count histogram (copy = blockIdx & 7) ----------------
// Measured R9: a cross-XCD scattered write costs one 64B line migration+writeback
// regardless of payload. All structures keep each cache line owned by one XCD.

__global__ void k_zero(uint4* p, int n16) {
    int i = blockIdx.x * blockDim.x + threadIdx.x;
    if (i < n16) p[i] = make_uint4(0, 0, 0, 0);
}

__global__ void k_hist8c(const int* __restrict__ ei, int* __restrict__ cnt8, int e) {
    int i = blockIdx.x * blockDim.x + threadIdx.x;
    if (i < e) {
        int d = ei[N_EDGES + i];
        int c = blockIdx.x & 7;
        atomicAdd(&cnt8[(size_t)c * N_NODES + d], 1);
    }
}

__global__ void k_reduce(const int* __restrict__ cnt8, int* __restrict__ cnt, int n) {
    int i = blockIdx.x * blockDim.x + threadIdx.x;
    if (i < n) {
        int c = 0;
#pragma unroll
        for (int k = 0; k < 8; k++) c += cnt8[(size_t)k * N_NODES + i];
        cnt[i] = c;
    }
}

// ---------------- hierarchical exclusive scan ----------------
__launch_bounds__(256)
__global__ void k_bsum(const int* __restrict__ cnt, int* __restrict__ bsum, int n) {
    int b = blockIdx.x, tid = threadIdx.x;
    int base = b * 1024 + tid * 4;
    int s = 0;
#pragma unroll
    for (int j = 0; j < 4; j++)
        if (base + j < n) s += cnt[base + j];
    for (int off = 32; off; off >>= 1) s += __shfl_down(s, off, 64);
    __shared__ int ws[4];
    if ((tid & 63) == 0) ws[tid >> 6] = s;
    __syncthreads();
    if (tid == 0) bsum[b] = ws[0] + ws[1] + ws[2] + ws[3];
}

__launch_bounds__(128)
__global__ void k_bscan(int* bsum, int nb, int* row_last) {
    __shared__ int ls[128];
    int tid = threadIdx.x;
    int v = (tid < nb) ? bsum[tid] : 0;
    ls[tid] = v;
    __syncthreads();
    for (int off = 1; off < 128; off <<= 1) {
        int t = (tid >= off) ? ls[tid - off] : 0;
        __syncthreads();
        ls[tid] += t;
        __syncthreads();
    }
    int ex = tid ? ls[tid - 1] : 0;
    if (tid < nb) bsum[tid] = ex;
    if (tid == 0) *row_last = N_EDGES;
}

__launch_bounds__(256)
__global__ void k_scan2(int* __restrict__ cnt_pos, const int* __restrict__ boff,
                        int* __restrict__ row, int n) {
    __shared__ int ls[256];
    int b = blockIdx.x, tid = threadIdx.x;
    int base = b * 1024 + tid * 4;
    int v[4];
    int s = 0;
#pragma unroll
    for (int j = 0; j < 4; j++) {
        v[j] = (base + j < n) ? cnt_pos[base + j] : 0;
        s += v[j];
    }
    ls[tid] = s;
    __syncthreads();
    for (int off = 1; off < 256; off <<= 1) {
        int t = (tid >= off) ? ls[tid - off] : 0;
        __syncthreads();
        ls[tid] += t;
        __syncthreads();
    }
    int run = boff[b] + (tid ? ls[tid - 1] : 0);
#pragma unroll
    for (int j = 0; j < 4; j++) {
        int node = base + j;
        if (node < n) {
            row[node] = run;
            run += v[j];
        }
    }
}

// (copy,bucket) stage cursors: bucket segment = CSR range, subdivided by copy
__global__ void k_bucketcur(const int* __restrict__ cnt8, const int* __restrict__ row,
                            int* __restrict__ cur8b) {
    int b = blockIdx.x * blockDim.x + threadIdx.x;
    if (b >= NBK) return;
    int n0 = b * NPBK;
    int run = row[n0];
#pragma unroll
    for (int c = 0; c < 8; c++) {
        cur8b[(size_t)c * NBK + b] = run;
        int s = 0;
#pragma unroll
        for (int j = 0; j < NPBK; j++) s += cnt8[(size_t)c * N_NODES + n0 + j];
        run += s;
    }
}

// phase A: append to XCD-private (copy,bucket) slice — dense, migration-free frontier
__global__ void k_placeA(const int* __restrict__ ei, const float* __restrict__ w,
                         int* __restrict__ cur8b, int2* __restrict__ stage, int e) {
    int i = blockIdx.x * blockDim.x + threadIdx.x;
    if (i < e) {
        int s = ei[i];
        int d = ei[N_EDGES + i];
        int c = blockIdx.x & 7;
        int b = d >> 4;
        int local = d & (NPBK - 1);
        int p = atomicAdd(&cur8b[(size_t)c * NBK + b], 1);
        stage[p] = make_int2((local << 17) | s, __float_as_int(w[i]));
    }
}

// phase B: one wave per bucket; sequential stage read, dense final write window
__launch_bounds__(256)
__global__ void k_placeB(const int2* __restrict__ stage, const int* __restrict__ row,
                         unsigned int* __restrict__ edges) {
    __shared__ int cur[4 * NPBK];
    int wave = threadIdx.x >> 6;
    int lane = threadIdx.x & 63;
    int b = blockIdx.x * 4 + wave;
    if (b >= NBK) return;
    int n0 = b * NPBK;
    if (lane < NPBK) cur[wave * NPBK + lane] = row[n0 + lane];
    __syncthreads();
    int lo = row[n0];
    int hi = row[n0 + NPBK];
    for (int j = lo + lane; j < hi; j += 64) {
        int2 rec = stage[j];
        int l = rec.x >> 17;
        int src = rec.x & 0x1FFFF;
        f16 hw = (f16)__int_as_float(rec.y);
        unsigned short wb = __builtin_bit_cast(unsigned short, hw);
        int p = atomicAdd(&cur[wave * NPBK + l], 1);
        edges[p] = ((unsigned int)src << 15) | (wb & 0x7FFF);
    }
}

// deg from CSR (sequential stream, no atomics): deg = 1 + sum w
__global__ void k_deg(const unsigned int* __restrict__ edges, const int* __restrict__ row,
                      float* __restrict__ dinv, int n) {
    int i = blockIdx.x * blockDim.x + threadIdx.x;
    if (i >= n) return;
    float s = 1.0f;
    int beg = row[i], end = row[i + 1];
    for (int j = beg; j < end; j++) s += unpackw(edges[j]);
    dinv[i] = rsqrtf(s);
}

// ---------------- fp32 -> fp16 conversions ----------------

__global__ void k_cvt(const float* __restrict__ X, f16* __restrict__ Y, int n8) {
    int i = blockIdx.x * blockDim.x + threadIdx.x;
    if (i < n8) {
        float4 a = ((const float4*)X)[i * 2];
        float4 b = ((const float4*)X)[i * 2 + 1];
        f16x8 o;
        o[0] = (f16)a.x; o[1] = (f16)a.y; o[2] = (f16)a.z; o[3] = (f16)a.w;
        o[4] = (f16)b.x; o[5] = (f16)b.y; o[6] = (f16)b.z; o[7] = (f16)b.w;
        ((f16x8*)Y)[i] = o;
    }
}

__global__ void k_wt(const float* __restrict__ W, f16* __restrict__ Wt) {
    int t = threadIdx.x;
#pragma unroll
    for (int it = 0; it < 64; it++) {
        int idx = t + it * 256;
        int k = idx >> 7, n = idx & 127;
        Wt[n * 128 + k] = (f16)W[idx];
    }
}

// ---------------- fp16 MFMA GEMM, epilogue scales rows by dinv ----------------
// H'[r] = dinv[r] * (A@W)[r] — folds the per-source GCN norm into the stored
// matrix so the aggregation needs no per-edge dinv gather (R11 change).

#define LDK 136

__launch_bounds__(256, 2)
__global__ void k_gemm16(const f16* __restrict__ A, const f16* __restrict__ Wt,
                         const float* __restrict__ dinv, f16* __restrict__ H, int nrows) {
    __shared__ f16 Ws[128 * LDK];
    int tid = threadIdx.x;
    int r0 = blockIdx.x * 128;
    int wave = tid >> 6;
    int lane = tid & 63;
    int lrow = lane & 15;
    int quad = lane >> 4;

    f16x8 a[2][4];
#pragma unroll
    for (int mt = 0; mt < 2; mt++) {
        int row = r0 + wave * 32 + mt * 16 + lrow;
#pragma unroll
        for (int kc = 0; kc < 4; kc++) {
            if (row < nrows)
                a[mt][kc] = *(const f16x8*)&A[(size_t)row * F + kc * 32 + quad * 8];
            else
                a[mt][kc] = (f16x8){};
        }
    }
#pragma unroll
    for (int it = 0; it < 8; it++) {
        int c = tid + it * 256;
        int rw = c >> 4;
        int off = (c & 15) * 8;
        *(f16x8*)&Ws[rw * LDK + off] = *(const f16x8*)&Wt[rw * 128 + off];
    }
    __syncthreads();

    f32x4 acc[2][8] = {};
#pragma unroll
    for (int kc = 0; kc < 4; kc++) {
        f16x8 b[8];
#pragma unroll
        for (int nt = 0; nt < 8; nt++)
            b[nt] = *(const f16x8*)&Ws[(nt * 16 + lrow) * LDK + kc * 32 + quad * 8];
#pragma unroll
        for (int nt = 0; nt < 8; nt++) {
            acc[0][nt] = __builtin_amdgcn_mfma_f32_16x16x32_f16(a[0][kc], b[nt], acc[0][nt], 0, 0, 0);
            acc[1][nt] = __builtin_amdgcn_mfma_f32_16x16x32_f16(a[1][kc], b[nt], acc[1][nt], 0, 0, 0);
        }
    }
    __syncthreads();
#pragma unroll
    for (int mt = 0; mt < 2; mt++) {
#pragma unroll
        for (int r = 0; r < 4; r++) {
            int lr = wave * 32 + mt * 16 + quad * 4 + r;
            int grow = r0 + lr;
            float dv = (grow < nrows) ? dinv[grow] : 0.f;
#pragma unroll
            for (int nt = 0; nt < 8; nt++)
                Ws[lr * 132 + nt * 16 + lrow] = (f16)(acc[mt][nt][r] * dv);
        }
    }
    __syncthreads();
#pragma unroll
    for (int it = 0; it < 8; it++) {
        int c = it * 256 + tid;
        int rw = c >> 4;
        int col = (c & 15) * 8;
        int grow = r0 + rw;
        if (grow < nrows)
            *(f16x8*)&H[(size_t)grow * F + col] = *(const f16x8*)&Ws[rw * 132 + col];
    }
}

// ---------------- aggregation: quarter-wave 16B gathers, no per-edge dinv ----------------
// out_i = relu( dd*(sum_e w_e*H'[src] + H'[i]) + b ),  dd = dinv[i], H' = dinv⊙(A@W)
// 16 lanes x f16x8 (16B) cover one 256B row; a wave processes 4 edges per gather inst.

__launch_bounds__(256)
__global__ void k_agg(const f16* __restrict__ H16, const int* __restrict__ row,
                      const unsigned int* __restrict__ edges,
                      const float* __restrict__ dinv, const float* __restrict__ bias,
                      f16* __restrict__ out, int n) {
    int node = blockIdx.x * 4 + (threadIdx.x >> 6);
    if (node >= n) return;
    int lane = threadIdx.x & 63;
    int qq = lane >> 4;        // quarter 0..3 -> edge t+qq
    int sub = lane & 15;       // 16 lanes x 8 f16 = 256B row
    float acc[8] = {0.f, 0.f, 0.f, 0.f, 0.f, 0.f, 0.f, 0.f};
    float acc2[8] = {0.f, 0.f, 0.f, 0.f, 0.f, 0.f, 0.f, 0.f};
    int beg = row[node], end = row[node + 1];
    int deg = end - beg;
    int t = qq;
    for (; t + 4 < deg; t += 8) {
        unsigned int e0 = edges[beg + t];
        unsigned int e1 = edges[beg + t + 4];
        float w0 = unpackw(e0);
        float w1 = unpackw(e1);
        f16x8 v0 = *(const f16x8*)&H16[(size_t)(e0 >> 15) * F + sub * 8];
        f16x8 v1 = *(const f16x8*)&H16[(size_t)(e1 >> 15) * F + sub * 8];
#pragma unroll
        for (int j = 0; j < 8; j++) {
            acc[j] = fmaf(w0, (float)v0[j], acc[j]);
            acc2[j] = fmaf(w1, (float)v1[j], acc2[j]);
        }
    }
    for (; t < deg; t += 4) {
        unsigned int e0 = edges[beg + t];
        float w0 = unpackw(e0);
        f16x8 v0 = *(const f16x8*)&H16[(size_t)(e0 >> 15) * F + sub * 8];
#pragma unroll
        for (int j = 0; j < 8; j++)
            acc[j] = fmaf(w0, (float)v0[j], acc[j]);
    }
#pragma unroll
    for (int j = 0; j < 8; j++) {
        acc[j] += acc2[j];
        acc[j] += __shfl_xor(acc[j], 16, 64);
        acc[j] += __shfl_xor(acc[j], 32, 64);
    }
    if (lane < 16) {
        float dd = dinv[node];
        f16x8 h = *(const f16x8*)&H16[(size_t)node * F + lane * 8];
        float4 b0 = *(const float4*)&bias[lane * 8];
        float4 b1 = *(const float4*)&bias[lane * 8 + 4];
        float bb[8] = {b0.x, b0.y, b0.z, b0.w, b1.x, b1.y, b1.z, b1.w};
        f16x8 o;
#pragma unroll
        for (int j = 0; j < 8; j++) {
            float r = fmaxf(fmaf(dd, acc[j] + (float)h[j], bb[j]), 0.f);
            o[j] = (f16)r;
        }
        *(f16x8*)&out[(size_t)node * F + lane * 8] = o;
    }
}

// agg3 fused with final dot: s'[node] = dinv[node] * ( relu(agg3) . Wfin )
__launch_bounds__(256)
__global__ void k_agg_dot(const f16* __restrict__ H16, const int* __restrict__ row,
                          const unsigned int* __restrict__ edges,
                          const float* __restrict__ dinv, const float* __restrict__ bias,
                          const float* __restrict__ Wf, float* __restrict__ sout, int n) {
    int node = blockIdx.x * 4 + (threadIdx.x >> 6);
    if (node >= n) return;
    int lane = threadIdx.x & 63;
    int qq = lane >> 4;
    int sub = lane & 15;
    float acc[8] = {0.f, 0.f, 0.f, 0.f, 0.f, 0.f, 0.f, 0.f};
    float acc2[8] = {0.f, 0.f, 0.f, 0.f, 0.f, 0.f, 0.f, 0.f};
    int beg = row[node], end = row[node + 1];
    int deg = end - beg;
    int t = qq;
    for (; t + 4 < deg; t += 8) {
        unsigned int e0 = edges[beg + t];
        unsigned int e1 = edges[beg + t + 4];
        float w0 = unpackw(e0);
        float w1 = unpackw(e1);
        f16x8 v0 = *(const f16x8*)&H16[(size_t)(e0 >> 15) * F + sub * 8];
        f16x8 v1 = *(const f16x8*)&H16[(size_t)(e1 >> 15) * F + sub * 8];
#pragma unroll
        for (int j = 0; j < 8; j++) {
            acc[j] = fmaf(w0, (float)v0[j], acc[j]);
            acc2[j] = fmaf(w1, (float)v1[j], acc2[j]);
        }
    }
    for (; t < deg; t += 4) {
        unsigned int e0 = edges[beg + t];
        float w0 = unpackw(e0);
        f16x8 v0 = *(const f16x8*)&H16[(size_t)(e0 >> 15) * F + sub * 8];
#pragma unroll
        for (int j = 0; j < 8; j++)
            acc[j] = fmaf(w0, (float)v0[j], acc[j]);
    }
#pragma unroll
    for (int j = 0; j < 8; j++) {
        acc[j] += acc2[j];
        acc[j] += __shfl_xor(acc[j], 16, 64);
        acc[j] += __shfl_xor(acc[j], 32, 64);
    }
    if (lane < 16) {
        float dd = dinv[node];
        f16x8 h = *(const f16x8*)&H16[(size_t)node * F + lane * 8];
        float4 b0 = *(const float4*)&bias[lane * 8];
        float4 b1 = *(const float4*)&bias[lane * 8 + 4];
        float bb[8] = {b0.x, b0.y, b0.z, b0.w, b1.x, b1.y, b1.z, b1.w};
        float4 w0 = *(const float4*)&Wf[lane * 8];
        float4 w1 = *(const float4*)&Wf[lane * 8 + 4];
        float ww[8] = {w0.x, w0.y, w0.z, w0.w, w1.x, w1.y, w1.z, w1.w};
        float p = 0.f;
#pragma unroll
        for (int j = 0; j < 8; j++)
            p += fmaxf(fmaf(dd, acc[j] + (float)h[j], bb[j]), 0.f) * ww[j];
        p += __shfl_xor(p, 8, 64);
        p += __shfl_xor(p, 4, 64);
        p += __shfl_xor(p, 2, 64);
        p += __shfl_xor(p, 1, 64);
        if (lane == 0) sout[node] = dd * p;   // s' = dinv * s
    }
}

__global__ void k_aggs(const float* __restrict__ s, const int* __restrict__ row,
                       const unsigned int* __restrict__ edges,
                       const float* __restrict__ dinv, const float* __restrict__ bf,
                       float* __restrict__ out, int n) {
    int i = blockIdx.x * blockDim.x + threadIdx.x;
    if (i >= n) return;
    float dd = dinv[i];
    float ae = s[i];   // self term: s'[i] already dinv-scaled
    int beg = row[i], end = row[i + 1];
    for (int j = beg; j < end; j++) {
        unsigned int p = edges[j];
        ae = fmaf(unpackw(p), s[p >> 15], ae);
    }
    out[i] = fmaf(dd, ae, bf[0]);
}

// ---------------- host launch ----------------

extern "C" void kernel_launch(void* const* d_in, const int* in_sizes, int n_in,
                              void* d_out, int out_size, void* d_ws, size_t ws_size,
                              hipStream_t stream) {
    const float* x    = (const float*)d_in[0];
    const int*   ei   = (const int*)d_in[1];
    const float* ew   = (const float*)d_in[2];
    const float* Win  = (const float*)d_in[3];
    const float* bin  = (const float*)d_in[4];
    const float* Wmid = (const float*)d_in[5];
    const float* bmid = (const float*)d_in[6];
    const float* Wfin = (const float*)d_in[7];
    const float* bfin = (const float*)d_in[8];
    float* out = (float*)d_out;

    char* ws = (char*)d_ws;
    size_t off = 0;
    auto alloc = [&](size_t bytes) -> char* {
        char* p = ws + off;
        off = (off + bytes + 255) & ~(size_t)255;
        return p;
    };
    float* dinv  = (float*)alloc((size_t)N_NODES * 4);
    int*   row   = (int*)alloc((size_t)(N_NODES + 1) * 4);
    int*   pos   = (int*)alloc((size_t)N_NODES * 4);
    unsigned int* edges = (unsigned int*)alloc((size_t)N_EDGES * 4);
    int*   bsum  = (int*)alloc(128 * 4);
    f16*   wtin  = (f16*)alloc(128 * 128 * 2);
    f16*   wtmid = (f16*)alloc(128 * 128 * 2);
    f16*   H16   = (f16*)alloc((size_t)N_NODES * F * 2);   // gemm out (dinv-scaled) / agg in
    f16*   AB16  = (f16*)alloc((size_t)N_NODES * F * 2);   // x16 -> agg out chain
    // aliased into H16's 25.6MB (all consumed before gemm1 writes H16):
    int*  cnt8  = (int*)H16;                                      // 3.2 MB
    int*  cur8b = (int*)((char*)H16 + (size_t)8 * N_NODES * 4);   // 0.2 MB
    int2* stage = (int2*)((char*)H16 + (size_t)8 * N_NODES * 4 + (size_t)8 * NBK * 4 + 256);
    float* sbuf = (float*)AB16;  // aliased: consumed by gemm3 before agg_dot writes

    dim3 b256(256);
    int gN = (N_NODES + 255) / 256;
    int gE = (N_EDGES + 255) / 256;
    int gW = (N_NODES + 3) / 4;
    int gG = (N_NODES + 127) / 128;
    int gS = (N_NODES + 1023) / 1024;
    int n16 = (int)(((size_t)8 * N_NODES * 4) / 16);
    int gZ = (n16 + 255) / 256;
    int n8 = N_NODES * F / 8;
    int gC = (n8 + 255) / 256;
    int gBC = (NBK + 255) / 256;
    int gPB = (NBK + 3) / 4;

    hipLaunchKernelGGL(k_zero, dim3(gZ), b256, 0, stream, (uint4*)cnt8, n16);
    hipLaunchKernelGGL(k_hist8c, dim3(gE), b256, 0, stream, ei, cnt8, N_EDGES);
    hipLaunchKernelGGL(k_reduce, dim3(gN), b256, 0, stream, cnt8, pos, N_NODES);
    hipLaunchKernelGGL(k_bsum, dim3(gS), b256, 0, stream, pos, bsum, N_NODES);
    hipLaunchKernelGGL(k_bscan, dim3(1), dim3(128), 0, stream, bsum, gS, &row[N_NODES]);
    hipLaunchKernelGGL(k_scan2, dim3(gS), b256, 0, stream, pos, bsum, row, N_NODES);
    hipLaunchKernelGGL(k_bucketcur, dim3(gBC), b256, 0, stream, cnt8, row, cur8b);
    hipLaunchKernelGGL(k_placeA, dim3(gE), b256, 0, stream, ei, ew, cur8b, stage, N_EDGES);
    hipLaunchKernelGGL(k_placeB, dim3(gPB), b256, 0, stream, stage, row, edges);
    hipLaunchKernelGGL(k_deg, dim3(gN), b256, 0, stream, edges, row, dinv, N_NODES);
    hipLaunchKernelGGL(k_cvt, dim3(gC), b256, 0, stream, x, AB16, n8);
    hipLaunchKernelGGL(k_wt, dim3(1), b256, 0, stream, Win, wtin);
    hipLaunchKernelGGL(k_wt, dim3(1), b256, 0, stream, Wmid, wtmid);

    hipLaunchKernelGGL(k_gemm16, dim3(gG), b256, 0, stream, AB16, wtin, dinv, H16, N_NODES);
    hipLaunchKernelGGL(k_agg, dim3(gW), b256, 0, stream, H16, row, edges, dinv, bin, AB16, N_NODES);
    hipLaunchKernelGGL(k_gemm16, dim3(gG), b256, 0, stream, AB16, wtmid, dinv, H16, N_NODES);
    hipLaunchKernelGGL(k_agg, dim3(gW), b256, 0, stream, H16, row, edges, dinv, bmid, AB16, N_NODES);
    hipLaunchKernelGGL(k_gemm16, dim3(gG), b256, 0, stream, AB16, wtmid, dinv, H16, N_NODES);
    hipLaunchKernelGGL(k_agg_dot, dim3(gW), b256, 0, stream, H16, row, edges, dinv, bmid, Wfin, sbuf, N_NODES);
    hipLaunchKernelGGL(k_aggs, dim3(gN), b256, 0, stream, sbuf, row, edges, dinv, bfin, out, N_NODES);
}